// Round 9
// baseline (4124.514 us; speedup 1.0000x reference)
//
#include <hip/hip_runtime.h>

// Problem constants (from reference)
#define NN 50000      // nodes
#define NE 300000     // edges
#define FEA 64        // edge feature dim
#define HD 256        // hidden
#define NG 256        // graphs
#define NL 4          // layers
#define OD 128        // out dim
#define NCH 16        // edge chunks (fp32 msgbuf must fit in h0hb region)
#define ECH (NE / NCH)
#define SP 72         // LDS row stride in u16 (64 + 8 pad: 16B-aligned, 2-way bank alias = free)
#define SCB ((NN + 255) / 256)   // scan blocks = 196

typedef unsigned short u16;
typedef unsigned int u32;
typedef __attribute__((ext_vector_type(8))) short short8;
typedef __attribute__((ext_vector_type(4))) float f32x4;

__device__ __forceinline__ float bf2f(u16 u) {
    union { u32 i; float f; } v; v.i = ((u32)u) << 16; return v.f;
}
__device__ __forceinline__ u16 f2bf(float f) {
    union { float f; u32 i; } v; v.f = f;
    u32 b = v.i;
    u32 r = (b + 0x7FFFu + ((b >> 16) & 1u)) >> 16;
    return (u16)r;
}

// ---------------------------------------------------------------------------
// Tiled MFMA GEMM: C[M,256] = epi(A[M,K] @ (Bhi+Blo)[256,K]^T + bias)
// Split-bf16 weights (systematic error is what survives graph pooling).
// Tile 128x128, BK=64, 4 waves (2x2), 4x4 16x16x32 frags, 2 MFMAs per pair.
// ASRC 0: A = bf16 rows [M,K]
// ASRC 1: A = fp32 eattr gathered via perm (K=64), cvt to bf16 in staging
// EPI 0: relu -> bf16 store to C
// EPI 2: e + x[src] -> relu -> fp32 store to msgbuf (edges sorted by dst)
// EPI 3: relu -> bf16 store + BN sum/sumsq atomics
// ---------------------------------------------------------------------------
template<int EPI, int ASRC>
__global__ __launch_bounds__(256, 2) void gemm_k(
    const u16* __restrict__ A, const float* __restrict__ A32,
    const int* __restrict__ perm, int e0,
    const u16* __restrict__ Bt, const u16* __restrict__ Btl,
    const float* __restrict__ bias, int M, int K,
    u16* __restrict__ C,
    const int* __restrict__ srcI,
    const u16* __restrict__ xb, float* __restrict__ msgf,
    float* __restrict__ bns, float* __restrict__ bnq)
{
    __shared__ __align__(16) u16 ldsA[128 * SP];
    __shared__ __align__(16) u16 ldsB[128 * SP];
    __shared__ __align__(16) u16 ldsBl[128 * SP];
    const int tid = threadIdx.x;
    const int lane = tid & 63;
    const int w = tid >> 6;
    const int wm = w & 1, wn = w >> 1;
    const int q = lane >> 4, c15 = lane & 15;
    const int m0 = blockIdx.x * 128;
    const int n0 = blockIdx.y * 128;

    f32x4 acc[4][4];
#pragma unroll
    for (int i = 0; i < 4; ++i)
#pragma unroll
        for (int j = 0; j < 4; ++j) acc[i][j] = (f32x4)0.0f;

    for (int k0 = 0; k0 < K; k0 += 64) {
        if (ASRC == 1) {
            // gather fp32 edge-attr rows via perm, cvt to bf16 (K=64, runs once)
#pragma unroll
            for (int it = 0; it < 8; ++it) {
                const int idx = it * 256 + tid;   // 0..2047 float4-slots
                const int m = idx >> 4;           // row 0..127
                const int fq = idx & 15;          // float4 within 64-float row
                int er = m0 + m; if (er > M - 1) er = M - 1;
                const float4 v = *(const float4*)(A32 + (size_t)perm[e0 + er] * FEA + fq * 4);
                u16* d = &ldsA[m * SP + fq * 4];
                d[0] = f2bf(v.x); d[1] = f2bf(v.y); d[2] = f2bf(v.z); d[3] = f2bf(v.w);
            }
        } else {
#pragma unroll
            for (int it = 0; it < 4; ++it) {
                const int i = it * 256 + tid;
                const int m = i >> 3;
                const int kb = i & 7;
                int rowA = m0 + m; if (rowA > M - 1) rowA = M - 1;
                *(short8*)&ldsA[m * SP + kb * 8] =
                    *(const short8*)(A + (size_t)rowA * K + k0 + kb * 8);
            }
        }
#pragma unroll
        for (int it = 0; it < 4; ++it) {
            const int i = it * 256 + tid;
            const int m = i >> 3;
            const int kb = i & 7;
            *(short8*)&ldsB[m * SP + kb * 8] =
                *(const short8*)(Bt + (size_t)(n0 + m) * K + k0 + kb * 8);
            *(short8*)&ldsBl[m * SP + kb * 8] =
                *(const short8*)(Btl + (size_t)(n0 + m) * K + k0 + kb * 8);
        }
        __syncthreads();
#pragma unroll
        for (int s = 0; s < 2; ++s) {
            short8 af[4], bh[4], bl[4];
#pragma unroll
            for (int t = 0; t < 4; ++t) {
                const int kga = s * 4 + q;
                const int mm = wm * 64 + t * 16 + c15;
                af[t] = *(const short8*)&ldsA[mm * SP + kga * 8];
                const int nn = wn * 64 + t * 16 + c15;
                bh[t] = *(const short8*)&ldsB[nn * SP + kga * 8];
                bl[t] = *(const short8*)&ldsBl[nn * SP + kga * 8];
            }
#pragma unroll
            for (int tm = 0; tm < 4; ++tm)
#pragma unroll
                for (int tn = 0; tn < 4; ++tn) {
                    acc[tm][tn] = __builtin_amdgcn_mfma_f32_16x16x32_bf16(
                        af[tm], bh[tn], acc[tm][tn], 0, 0, 0);
                    acc[tm][tn] = __builtin_amdgcn_mfma_f32_16x16x32_bf16(
                        af[tm], bl[tn], acc[tm][tn], 0, 0, 0);
                }
        }
        __syncthreads();
    }

    float biasf[4];
#pragma unroll
    for (int tn = 0; tn < 4; ++tn)
        biasf[tn] = bias[n0 + wn * 64 + tn * 16 + c15];

    if (EPI == 2) {
        // msg = relu(e + x[src]) -> fp32 msgbuf (streaming, no atomics)
#pragma unroll
        for (int tm = 0; tm < 4; ++tm) {
#pragma unroll
            for (int r = 0; r < 4; ++r) {
                const int erow = m0 + wm * 64 + tm * 16 + q * 4 + r;
                if (erow < M) {
                    const int sn = srcI[erow];
                    const u16* xr = xb + (size_t)sn * HD;
#pragma unroll
                    for (int tn = 0; tn < 4; ++tn) {
                        const int col = n0 + wn * 64 + tn * 16 + c15;
                        float msg = acc[tm][tn][r] + biasf[tn] + bf2f(xr[col]);
                        msg = msg > 0.0f ? msg : 0.0f;
                        msgf[(size_t)erow * HD + col] = msg;
                    }
                }
            }
        }
    } else {
        float ps[4] = {0, 0, 0, 0}, pq[4] = {0, 0, 0, 0};
#pragma unroll
        for (int tm = 0; tm < 4; ++tm) {
#pragma unroll
            for (int r = 0; r < 4; ++r) {
                const int grow = m0 + wm * 64 + tm * 16 + q * 4 + r;
                if (grow < M) {
#pragma unroll
                    for (int tn = 0; tn < 4; ++tn) {
                        const int col = n0 + wn * 64 + tn * 16 + c15;
                        float v = acc[tm][tn][r] + biasf[tn];
                        v = v > 0.0f ? v : 0.0f;  // relu
                        C[(size_t)grow * HD + col] = f2bf(v);
                        if (EPI == 3) { ps[tn] += v; pq[tn] += v * v; }
                    }
                }
            }
        }
        if (EPI == 3) {
#pragma unroll
            for (int tn = 0; tn < 4; ++tn) {
                float s = ps[tn], sq = pq[tn];
                s += __shfl_down(s, 32, 64);  sq += __shfl_down(sq, 32, 64);
                s += __shfl_down(s, 16, 64);  sq += __shfl_down(sq, 16, 64);
                if (q == 0) {
                    const int col = n0 + wn * 64 + tn * 16 + c15;
                    unsafeAtomicAdd(&bns[col], s);
                    unsafeAtomicAdd(&bnq[col], sq);
                }
            }
        }
    }
}

// segmented sum over sorted fp32 msgbuf: one block per node, one col per thread
__global__ __launch_bounds__(256) void segsum_k(
    const float* __restrict__ msg, const int* __restrict__ rowptr,
    int e0, float* __restrict__ aggr)
{
    const int n = blockIdx.x, t = threadIdx.x;
    int lo = rowptr[n], hi = rowptr[n + 1];
    if (lo < e0) lo = e0;
    const int e1 = e0 + ECH;
    if (hi > e1) hi = e1;
    if (lo >= hi) return;
    float s = 0.0f;
    for (int e = lo; e < hi; ++e)
        s += msg[(size_t)(e - e0) * HD + t];
    unsafeAtomicAdd(&aggr[(size_t)n * HD + t], s);
}

// --------------------------- small helper kernels ---------------------------

// fp32 [L,K,N] -> split bf16 transposed [L,N,K] (hi + lo)
__global__ void transpose_k(const float* __restrict__ in, u16* __restrict__ oh,
                            u16* __restrict__ ol, int Kw, int Nw) {
    int i = blockIdx.x * blockDim.x + threadIdx.x;
    int tot = NL * Kw * Nw;
    if (i < tot) {
        int l = i / (Kw * Nw), rem = i % (Kw * Nw);
        int k = rem / Nw, n = rem % Nw;
        float wv = in[i];
        u16 hi = f2bf(wv);
        float lo = wv - bf2f(hi);
        size_t idx = (size_t)l * Kw * Nw + (size_t)n * Kw + k;
        oh[idx] = hi;
        ol[idx] = f2bf(lo);
    }
}

__global__ void cvt_k(const float* __restrict__ in, u16* __restrict__ outb, int tot) {
    int i = blockIdx.x * blockDim.x + threadIdx.x;
    if (i < tot) outb[i] = f2bf(in[i]);
}

__global__ void zero_layer_k(float* __restrict__ aggr, float* __restrict__ bns,
                             float* __restrict__ bnq) {
    int i = blockIdx.x * blockDim.x + threadIdx.x;
    if (i < NN * HD) aggr[i] = 0.0f;
    if (i < HD) { bns[i] = 0.0f; bnq[i] = 0.0f; }
}

__global__ void h0_k(const u16* __restrict__ xb, const float* __restrict__ aggr,
                     u16* __restrict__ h0, const float* __restrict__ epsv, int l) {
    int i = blockIdx.x * blockDim.x + threadIdx.x;
    if (i < NN * HD) {
        float e1 = 1.0f + epsv[l];
        h0[i] = f2bf(e1 * bf2f(xb[i]) + aggr[i]);
    }
}

__global__ void bnfin_k(const float* __restrict__ bns, const float* __restrict__ bnq,
                        const float* __restrict__ gamma, const float* __restrict__ beta,
                        int l, float* __restrict__ ab) {
    int c = threadIdx.x;
    float mu = bns[c] * (1.0f / (float)NN);
    float var = bnq[c] * (1.0f / (float)NN) - mu * mu;
    if (var < 0.0f) var = 0.0f;
    float a = gamma[l * HD + c] * rsqrtf(var + 1e-5f);
    float b = beta[l * HD + c] - mu * a;
    ab[c] = a; ab[HD + c] = b;
}

__global__ void bnapply_k(const u16* __restrict__ hb, const float* __restrict__ ab,
                          u16* __restrict__ xb) {
    int i = blockIdx.x * blockDim.x + threadIdx.x;
    if (i < NN * HD) {
        int c = i & (HD - 1);
        xb[i] = f2bf(ab[c] * bf2f(hb[i]) + ab[HD + c]);
    }
}

// ---- edge counting-sort by dst (hierarchical scan) ----

__global__ void zeroi_k(int* __restrict__ a, int n) {
    int i = blockIdx.x * blockDim.x + threadIdx.x;
    if (i < n) a[i] = 0;
}

__global__ void hist_k(const int* __restrict__ dst, int* __restrict__ hist) {
    int e = blockIdx.x * blockDim.x + threadIdx.x;
    if (e < NE) atomicAdd(&hist[dst[e]], 1);
}

__global__ void sumblk_k(const int* __restrict__ hist, int* __restrict__ psum) {
    __shared__ int red[256];
    int b = blockIdx.x, t = threadIdx.x, i = b * 256 + t;
    red[t] = (i < NN) ? hist[i] : 0;
    __syncthreads();
    for (int o = 128; o > 0; o >>= 1) {
        if (t < o) red[t] += red[t + o];
        __syncthreads();
    }
    if (t == 0) psum[b] = red[0];
}

__global__ void scanblk_k(int* __restrict__ psum) {
    __shared__ int sc[256];
    int t = threadIdx.x;
    int v = (t < SCB) ? psum[t] : 0;
    sc[t] = v; __syncthreads();
    for (int o = 1; o < 256; o <<= 1) {
        int x = (t >= o) ? sc[t - o] : 0;
        __syncthreads(); sc[t] += x; __syncthreads();
    }
    if (t < SCB) psum[t] = sc[t] - v;   // exclusive
}

__global__ void scanfin_k(const int* __restrict__ hist, const int* __restrict__ psum,
                          int* __restrict__ rowptr) {
    __shared__ int sc[256];
    int b = blockIdx.x, t = threadIdx.x, i = b * 256 + t;
    int v = (i < NN) ? hist[i] : 0;
    sc[t] = v; __syncthreads();
    for (int o = 1; o < 256; o <<= 1) {
        int x = (t >= o) ? sc[t - o] : 0;
        __syncthreads(); sc[t] += x; __syncthreads();
    }
    if (i < NN) rowptr[i] = psum[b] + sc[t] - v;
    if (i == NN - 1) rowptr[NN] = psum[b] + sc[t];
}

__global__ void copyi_k(const int* __restrict__ src, int* __restrict__ dst, int n) {
    int i = blockIdx.x * blockDim.x + threadIdx.x;
    if (i < n) dst[i] = src[i];
}

__global__ void scatter_k(const int* __restrict__ dst, int* __restrict__ next,
                          int* __restrict__ perm) {
    int e = blockIdx.x * blockDim.x + threadIdx.x;
    if (e < NE) {
        int p = atomicAdd(&next[dst[e]], 1);
        perm[p] = e;
    }
}

__global__ void permsd_k(const int* __restrict__ eidx, const int* __restrict__ perm,
                         int* __restrict__ srcS) {
    int i = blockIdx.x * blockDim.x + threadIdx.x;
    if (i < NE) srcS[i] = eidx[perm[i]];
}

// ---- graph pooling ----

__global__ void zcnt_k(int* __restrict__ cnts) {
    if (threadIdx.x < NG) cnts[threadIdx.x] = 0;
}

__global__ void count_k(const int* __restrict__ batch, int* __restrict__ cnts) {
    int i = blockIdx.x * blockDim.x + threadIdx.x;
    if (i < NN) atomicAdd(&cnts[batch[i]], 1);
}

__global__ void offs_k(const int* __restrict__ cnts, int* __restrict__ offs) {
    if (threadIdx.x == 0) {
        int a = 0;
        for (int g = 0; g < NG; ++g) { offs[g] = a; a += cnts[g]; }
        offs[NG] = a;
    }
}

__global__ void pool_layer_k(const u16* __restrict__ xb, const int* __restrict__ offs,
                             float* __restrict__ pooled, int l) {
    int g = blockIdx.x, t = threadIdx.x;
    int lo = offs[g], hi = offs[g + 1];
    float s = 0.0f;
    for (int n = lo; n < hi; ++n) s += bf2f(xb[(size_t)n * HD + t]);
    int c = hi - lo; if (c < 1) c = 1;
    pooled[(size_t)g * (NL * HD) + l * HD + t] = s / (float)c;
}

__global__ void fc_k(const float* __restrict__ pooled,
                     const float* __restrict__ W1, const float* __restrict__ b1,
                     const float* __restrict__ W4, const float* __restrict__ b4,
                     float* __restrict__ out) {
    __shared__ float pl[NL * HD];
    __shared__ float hm[HD];
    int g = blockIdx.x, t = threadIdx.x;
#pragma unroll
    for (int j = 0; j < 4; ++j) pl[t + j * 256] = pooled[(size_t)g * 1024 + t + j * 256];
    __syncthreads();
    float a = b1[t];
    for (int k = 0; k < 1024; ++k) a += pl[k] * W1[k * 256 + t];
    hm[t] = a > 0.0f ? a : 0.0f;
    __syncthreads();
    if (t < OD) {
        float o = b4[t];
        for (int k = 0; k < 256; ++k) o += hm[k] * W4[k * OD + t];
        out[g * OD + t] = o;
    }
}

// ---------------------------------------------------------------------------

extern "C" void kernel_launch(void* const* d_in, const int* in_sizes, int n_in,
                              void* d_out, int out_size, void* d_ws, size_t ws_size,
                              hipStream_t stream) {
    const float* x_in  = (const float*)d_in[0];
    const int*   eidx  = (const int*)d_in[1];
    const float* eattr = (const float*)d_in[2];
    const int*   batch = (const int*)d_in[3];
    const float* bW1   = (const float*)d_in[4];
    const float* bb1   = (const float*)d_in[5];
    const float* bW2   = (const float*)d_in[6];
    const float* bb2   = (const float*)d_in[7];
    const float* mW1   = (const float*)d_in[8];
    const float* mb1   = (const float*)d_in[9];
    const float* mW2   = (const float*)d_in[10];
    const float* mb2   = (const float*)d_in[11];
    const float* epsv  = (const float*)d_in[12];
    const float* gamma = (const float*)d_in[13];
    const float* beta  = (const float*)d_in[14];
    const float* fc1W  = (const float*)d_in[15];
    const float* fc1b  = (const float*)d_in[16];
    const float* fc4W  = (const float*)d_in[17];
    const float* fc4b  = (const float*)d_in[18];
    float* out = (float*)d_out;
    (void)in_sizes; (void)n_in; (void)out_size; (void)ws_size;

    // ---- workspace carve (~130 MB; round-4's ~156 MB ran without fault) ----
    size_t off = 0;
    auto alloc = [&](size_t bytes) -> char* {
        char* r = (char*)d_ws + off;
        off = (off + bytes + 255) & ~(size_t)255;
        return r;
    };
    u16*   xb   = (u16*)alloc((size_t)NN * HD * 2);    // 25.6 MB node feats, bf16
    float* aggr = (float*)alloc((size_t)NN * HD * 4);  // 51.2 MB aggregate, fp32
    u16*   h0hb = (u16*)alloc((size_t)NN * HD * 2);    // 25.6 MB: msgbuf(edge) / h0,hb(node)
    u16*   W1t  = (u16*)alloc((size_t)NL * FEA * HD * 2);
    u16*   W1tl = (u16*)alloc((size_t)NL * FEA * HD * 2);
    u16*   W2t  = (u16*)alloc((size_t)NL * HD * HD * 2);
    u16*   W2tl = (u16*)alloc((size_t)NL * HD * HD * 2);
    u16*   M1t  = (u16*)alloc((size_t)NL * HD * HD * 2);
    u16*   M1tl = (u16*)alloc((size_t)NL * HD * HD * 2);
    u16*   M2t  = (u16*)alloc((size_t)NL * HD * HD * 2);
    u16*   M2tl = (u16*)alloc((size_t)NL * HD * HD * 2);
    float* bns  = (float*)alloc(HD * 4);
    float* bnq  = (float*)alloc(HD * 4);
    float* ab   = (float*)alloc(2 * HD * 4);
    int*   cnts = (int*)alloc(NG * 4);
    int*   offs = (int*)alloc((NG + 1) * 4);
    float* pooled = (float*)alloc((size_t)NG * NL * HD * 4);
    int*   hist  = (int*)alloc((size_t)NN * 4);        // also reused as `next`
    int*   psum  = (int*)alloc((size_t)SCB * 4);
    int*   rowptr = (int*)alloc((size_t)(NN + 1) * 4);
    int*   perm  = (int*)alloc((size_t)NE * 4);
    int*   srcS  = (int*)alloc((size_t)NE * 4);
    // union region (25.6 MB): node phase T2 | edge phase T1 (9.6 MB @ NCH=16)
    u16* T2  = (u16*)alloc((size_t)NN * HD * 2);
    u16* T1  = T2;
    float* msgbuf = (float*)h0hb;   // 19.2 MB fp32 fits in 25.6 MB; dead during edge phase

    const int NEL = NN * HD;
    const int EB = (NEL + 255) / 256;
    const int NEB = (NE + 255) / 256;

    // weights: fp32 -> split bf16 (hi+lo), transposed to [N,K]
    transpose_k<<<(NL * FEA * HD + 255) / 256, 256, 0, stream>>>(bW1, W1t, W1tl, FEA, HD);
    transpose_k<<<(NL * HD * HD + 255) / 256, 256, 0, stream>>>(bW2, W2t, W2tl, HD, HD);
    transpose_k<<<(NL * HD * HD + 255) / 256, 256, 0, stream>>>(mW1, M1t, M1tl, HD, HD);
    transpose_k<<<(NL * HD * HD + 255) / 256, 256, 0, stream>>>(mW2, M2t, M2tl, HD, HD);

    cvt_k<<<EB, 256, 0, stream>>>(x_in, xb, NEL);

    // counting-sort edges by dst: hist -> hierarchical scan -> scatter perm
    zeroi_k<<<(NN + 255) / 256, 256, 0, stream>>>(hist, NN);
    hist_k<<<NEB, 256, 0, stream>>>(eidx + NE, hist);
    sumblk_k<<<SCB, 256, 0, stream>>>(hist, psum);
    scanblk_k<<<1, 256, 0, stream>>>(psum);
    scanfin_k<<<SCB, 256, 0, stream>>>(hist, psum, rowptr);
    copyi_k<<<(NN + 255) / 256, 256, 0, stream>>>(rowptr, hist, NN);   // hist = next
    scatter_k<<<NEB, 256, 0, stream>>>(eidx + NE, hist, perm);
    permsd_k<<<NEB, 256, 0, stream>>>(eidx, perm, srcS);

    zcnt_k<<<1, 256, 0, stream>>>(cnts);
    count_k<<<(NN + 255) / 256, 256, 0, stream>>>(batch, cnts);
    offs_k<<<1, 64, 0, stream>>>(cnts, offs);

    for (int l = 0; l < NL; ++l) {
        zero_layer_k<<<EB, 256, 0, stream>>>(aggr, bns, bnq);
        // edge path (sorted): gather-GEMM0 -> GEMM1+msg-write -> segmented sum
        for (int c = 0; c < NCH; ++c) {
            const int e0 = c * ECH;
            dim3 g1((ECH + 127) / 128, 2);
            gemm_k<0, 1><<<g1, 256, 0, stream>>>(
                nullptr, eattr, perm, e0,
                W1t + (size_t)l * FEA * HD, W1tl + (size_t)l * FEA * HD,
                bb1 + l * HD, ECH, FEA, T1,
                nullptr, nullptr, nullptr, nullptr, nullptr);
            gemm_k<2, 0><<<g1, 256, 0, stream>>>(
                T1, nullptr, nullptr, 0,
                W2t + (size_t)l * HD * HD, W2tl + (size_t)l * HD * HD,
                bb2 + l * HD, ECH, HD, nullptr,
                srcS + e0, xb, msgbuf, nullptr, nullptr);
            segsum_k<<<NN, 256, 0, stream>>>(msgbuf, rowptr, e0, aggr);
        }
        h0_k<<<EB, 256, 0, stream>>>(xb, aggr, h0hb, epsv, l);
        dim3 g2((NN + 127) / 128, 2);
        gemm_k<0, 0><<<g2, 256, 0, stream>>>(
            h0hb, nullptr, nullptr, 0,
            M1t + (size_t)l * HD * HD, M1tl + (size_t)l * HD * HD,
            mb1 + l * HD, NN, HD, T2,
            nullptr, nullptr, nullptr, nullptr, nullptr);
        gemm_k<3, 0><<<g2, 256, 0, stream>>>(
            T2, nullptr, nullptr, 0,
            M2t + (size_t)l * HD * HD, M2tl + (size_t)l * HD * HD,
            mb2 + l * HD, NN, HD, h0hb,
            nullptr, nullptr, nullptr, bns, bnq);
        bnfin_k<<<1, HD, 0, stream>>>(bns, bnq, gamma, beta, l, ab);
        bnapply_k<<<EB, 256, 0, stream>>>(h0hb, ab, xb);
        pool_layer_k<<<NG, HD, 0, stream>>>(xb, offs, pooled, l);
    }
    fc_k<<<NG, 256, 0, stream>>>(pooled, fc1W, fc1b, fc4W, fc4b, out);
}

// Round 10
// 2532.298 us; speedup vs baseline: 1.6288x; 1.6288x over previous
//
#include <hip/hip_runtime.h>

// Problem constants (from reference)
#define NN 50000      // nodes
#define NE 300000     // edges
#define FEA 64        // edge feature dim
#define HD 256        // hidden
#define NG 256        // graphs
#define NL 4          // layers
#define OD 128        // out dim
#define NCH 4         // edge chunks
#define ECH (NE / NCH)
#define SP 72         // LDS row stride in u16 (64 + 8 pad: 16B-aligned, 2-way bank alias = free)
#define SCB ((NN + 255) / 256)   // scan blocks = 196

typedef unsigned short u16;
typedef unsigned int u32;
typedef __attribute__((ext_vector_type(8))) short short8;
typedef __attribute__((ext_vector_type(4))) float f32x4;

__device__ __forceinline__ u16 f2h(float f) {
    union { _Float16 h; u16 u; } v; v.h = (_Float16)f; return v.u;
}
__device__ __forceinline__ float h2f(u16 u) {
    union { u16 u; _Float16 h; } v; v.u = u; return (float)v.h;
}

// ---------------------------------------------------------------------------
// Tiled MFMA GEMM: C[M,256] = epi(A[M,K] @ B[256,K]^T + bias), ALL fp16.
// fp16 (11-bit mantissa) keeps absmax ~8x below the all-bf16 pipeline's 6.35e-3
// without split weights -> single MFMA stream, 2 LDS buffers, 4 blocks/CU.
// Tile 128x128, BK=64, 4 waves (2x2), 4x4 16x16x32_f16 frags.
// ASRC 0: A = fp16 rows [M,K]
// ASRC 1: A = fp32 eattr gathered via perm (K=64), cvt to fp16 in staging
// EPI 0: relu -> fp16 store to C
// EPI 1: e + x[src] -> relu -> run-dedup atomicAdd aggr[dst] (edges sorted by dst)
// EPI 3: relu -> fp16 store + BN sum/sumsq atomics
// ---------------------------------------------------------------------------
template<int EPI, int ASRC>
__global__ __launch_bounds__(256, 4) void gemm_k(
    const u16* __restrict__ A, const float* __restrict__ A32,
    const int* __restrict__ perm, int e0,
    const u16* __restrict__ Bt,
    const float* __restrict__ bias, int M, int K,
    u16* __restrict__ C,
    const int* __restrict__ srcI, const int* __restrict__ dstI,
    const u16* __restrict__ xh, float* __restrict__ aggr,
    float* __restrict__ bns, float* __restrict__ bnq)
{
    __shared__ __align__(16) u16 ldsA[128 * SP];
    __shared__ __align__(16) u16 ldsB[128 * SP];
    const int tid = threadIdx.x;
    const int lane = tid & 63;
    const int w = tid >> 6;
    const int wm = w & 1, wn = w >> 1;
    const int q = lane >> 4, c15 = lane & 15;
    const int m0 = blockIdx.x * 128;
    const int n0 = blockIdx.y * 128;

    f32x4 acc[4][4];
#pragma unroll
    for (int i = 0; i < 4; ++i)
#pragma unroll
        for (int j = 0; j < 4; ++j) acc[i][j] = (f32x4)0.0f;

    for (int k0 = 0; k0 < K; k0 += 64) {
        if (ASRC == 1) {
            // gather fp32 edge-attr rows via perm, cvt to fp16 (K=64, runs once)
#pragma unroll
            for (int it = 0; it < 8; ++it) {
                const int idx = it * 256 + tid;   // 0..2047 float4-slots
                const int m = idx >> 4;           // row 0..127
                const int fq = idx & 15;          // float4 within 64-float row
                int er = m0 + m; if (er > M - 1) er = M - 1;
                const float4 v = *(const float4*)(A32 + (size_t)perm[e0 + er] * FEA + fq * 4);
                u16* d = &ldsA[m * SP + fq * 4];
                d[0] = f2h(v.x); d[1] = f2h(v.y); d[2] = f2h(v.z); d[3] = f2h(v.w);
            }
        } else {
#pragma unroll
            for (int it = 0; it < 4; ++it) {
                const int i = it * 256 + tid;
                const int m = i >> 3;
                const int kb = i & 7;
                int rowA = m0 + m; if (rowA > M - 1) rowA = M - 1;
                *(short8*)&ldsA[m * SP + kb * 8] =
                    *(const short8*)(A + (size_t)rowA * K + k0 + kb * 8);
            }
        }
#pragma unroll
        for (int it = 0; it < 4; ++it) {
            const int i = it * 256 + tid;
            const int m = i >> 3;
            const int kb = i & 7;
            *(short8*)&ldsB[m * SP + kb * 8] =
                *(const short8*)(Bt + (size_t)(n0 + m) * K + k0 + kb * 8);
        }
        __syncthreads();
#pragma unroll
        for (int s = 0; s < 2; ++s) {
            short8 af[4], bf[4];
#pragma unroll
            for (int t = 0; t < 4; ++t) {
                const int kga = s * 4 + q;
                const int mm = wm * 64 + t * 16 + c15;
                af[t] = *(const short8*)&ldsA[mm * SP + kga * 8];
                const int nn = wn * 64 + t * 16 + c15;
                bf[t] = *(const short8*)&ldsB[nn * SP + kga * 8];
            }
#pragma unroll
            for (int tm = 0; tm < 4; ++tm)
#pragma unroll
                for (int tn = 0; tn < 4; ++tn)
                    acc[tm][tn] = __builtin_amdgcn_mfma_f32_16x16x32_f16(
                        af[tm], bf[tn], acc[tm][tn], 0, 0, 0);
        }
        __syncthreads();
    }

    float biasf[4];
#pragma unroll
    for (int tn = 0; tn < 4; ++tn)
        biasf[tn] = bias[n0 + wn * 64 + tn * 16 + c15];

    if (EPI == 1) {
        // edges sorted by dst; each lane owns 4 consecutive edges -> run-dedup
#pragma unroll
        for (int tm = 0; tm < 4; ++tm) {
            const int base = m0 + wm * 64 + tm * 16 + q * 4;
            int sn[4], dn[4];
            bool val[4];
#pragma unroll
            for (int r = 0; r < 4; ++r) {
                const int erow = base + r;
                val[r] = erow < M;
                const int er = val[r] ? erow : (M - 1);
                sn[r] = srcI[er];
                dn[r] = dstI[er];
            }
#pragma unroll
            for (int tn = 0; tn < 4; ++tn) {
                const int col = n0 + wn * 64 + tn * 16 + c15;
                float accv = 0.0f;
                int cur = -1;
#pragma unroll
                for (int r = 0; r < 4; ++r) {
                    if (val[r]) {
                        float msg = acc[tm][tn][r] + biasf[tn]
                                  + h2f(xh[(size_t)sn[r] * HD + col]);
                        msg = msg > 0.0f ? msg : 0.0f;
                        if (dn[r] != cur) {
                            if (cur >= 0 && accv > 0.0f)
                                unsafeAtomicAdd(&aggr[(size_t)cur * HD + col], accv);
                            cur = dn[r];
                            accv = 0.0f;
                        }
                        accv += msg;
                    }
                }
                if (cur >= 0 && accv > 0.0f)
                    unsafeAtomicAdd(&aggr[(size_t)cur * HD + col], accv);
            }
        }
    } else {
        float ps[4] = {0, 0, 0, 0}, pq[4] = {0, 0, 0, 0};
#pragma unroll
        for (int tm = 0; tm < 4; ++tm) {
#pragma unroll
            for (int r = 0; r < 4; ++r) {
                const int grow = m0 + wm * 64 + tm * 16 + q * 4 + r;
                if (grow < M) {
#pragma unroll
                    for (int tn = 0; tn < 4; ++tn) {
                        const int col = n0 + wn * 64 + tn * 16 + c15;
                        float v = acc[tm][tn][r] + biasf[tn];
                        v = v > 0.0f ? v : 0.0f;  // relu
                        C[(size_t)grow * HD + col] = f2h(v);
                        if (EPI == 3) { ps[tn] += v; pq[tn] += v * v; }
                    }
                }
            }
        }
        if (EPI == 3) {
#pragma unroll
            for (int tn = 0; tn < 4; ++tn) {
                float s = ps[tn], sq = pq[tn];
                s += __shfl_down(s, 32, 64);  sq += __shfl_down(sq, 32, 64);
                s += __shfl_down(s, 16, 64);  sq += __shfl_down(sq, 16, 64);
                if (q == 0) {
                    const int col = n0 + wn * 64 + tn * 16 + c15;
                    unsafeAtomicAdd(&bns[col], s);
                    unsafeAtomicAdd(&bnq[col], sq);
                }
            }
        }
    }
}

// --------------------------- small helper kernels ---------------------------

// fp32 [L,K,N] -> fp16 transposed [L,N,K]
__global__ void transpose_k(const float* __restrict__ in, u16* __restrict__ oh,
                            int Kw, int Nw) {
    int i = blockIdx.x * blockDim.x + threadIdx.x;
    int tot = NL * Kw * Nw;
    if (i < tot) {
        int l = i / (Kw * Nw), rem = i % (Kw * Nw);
        int k = rem / Nw, n = rem % Nw;
        oh[(size_t)l * Kw * Nw + (size_t)n * Kw + k] = f2h(in[i]);
    }
}

__global__ void cvt_k(const float* __restrict__ in, u16* __restrict__ outh, int tot) {
    int i = blockIdx.x * blockDim.x + threadIdx.x;
    if (i < tot) outh[i] = f2h(in[i]);
}

__global__ void zero_layer_k(float* __restrict__ aggr, float* __restrict__ bns,
                             float* __restrict__ bnq) {
    int i = blockIdx.x * blockDim.x + threadIdx.x;
    if (i < NN * HD) aggr[i] = 0.0f;
    if (i < HD) { bns[i] = 0.0f; bnq[i] = 0.0f; }
}

__global__ void h0_k(const u16* __restrict__ xh, const float* __restrict__ aggr,
                     u16* __restrict__ h0, const float* __restrict__ epsv, int l) {
    int i = blockIdx.x * blockDim.x + threadIdx.x;
    if (i < NN * HD) {
        float e1 = 1.0f + epsv[l];
        h0[i] = f2h(e1 * h2f(xh[i]) + aggr[i]);
    }
}

__global__ void bnfin_k(const float* __restrict__ bns, const float* __restrict__ bnq,
                        const float* __restrict__ gamma, const float* __restrict__ beta,
                        int l, float* __restrict__ ab) {
    int c = threadIdx.x;
    float mu = bns[c] * (1.0f / (float)NN);
    float var = bnq[c] * (1.0f / (float)NN) - mu * mu;
    if (var < 0.0f) var = 0.0f;
    float a = gamma[l * HD + c] * rsqrtf(var + 1e-5f);
    float b = beta[l * HD + c] - mu * a;
    ab[c] = a; ab[HD + c] = b;
}

__global__ void bnapply_k(const u16* __restrict__ hb, const float* __restrict__ ab,
                          u16* __restrict__ xh) {
    int i = blockIdx.x * blockDim.x + threadIdx.x;
    if (i < NN * HD) {
        int c = i & (HD - 1);
        xh[i] = f2h(ab[c] * h2f(hb[i]) + ab[HD + c]);
    }
}

// ---- edge counting-sort by dst (hierarchical scan) ----

__global__ void zeroi_k(int* __restrict__ a, int n) {
    int i = blockIdx.x * blockDim.x + threadIdx.x;
    if (i < n) a[i] = 0;
}

__global__ void hist_k(const int* __restrict__ dst, int* __restrict__ hist) {
    int e = blockIdx.x * blockDim.x + threadIdx.x;
    if (e < NE) atomicAdd(&hist[dst[e]], 1);
}

__global__ void sumblk_k(const int* __restrict__ hist, int* __restrict__ psum) {
    __shared__ int red[256];
    int b = blockIdx.x, t = threadIdx.x, i = b * 256 + t;
    red[t] = (i < NN) ? hist[i] : 0;
    __syncthreads();
    for (int o = 128; o > 0; o >>= 1) {
        if (t < o) red[t] += red[t + o];
        __syncthreads();
    }
    if (t == 0) psum[b] = red[0];
}

__global__ void scanblk_k(int* __restrict__ psum) {
    __shared__ int sc[256];
    int t = threadIdx.x;
    int v = (t < SCB) ? psum[t] : 0;
    sc[t] = v; __syncthreads();
    for (int o = 1; o < 256; o <<= 1) {
        int x = (t >= o) ? sc[t - o] : 0;
        __syncthreads(); sc[t] += x; __syncthreads();
    }
    if (t < SCB) psum[t] = sc[t] - v;   // exclusive
}

__global__ void scanfin_k(const int* __restrict__ hist, const int* __restrict__ psum,
                          int* __restrict__ rowptr) {
    __shared__ int sc[256];
    int b = blockIdx.x, t = threadIdx.x, i = b * 256 + t;
    int v = (i < NN) ? hist[i] : 0;
    sc[t] = v; __syncthreads();
    for (int o = 1; o < 256; o <<= 1) {
        int x = (t >= o) ? sc[t - o] : 0;
        __syncthreads(); sc[t] += x; __syncthreads();
    }
    if (i < NN) rowptr[i] = psum[b] + sc[t] - v;
    if (i == NN - 1) rowptr[NN] = psum[b] + sc[t];
}

__global__ void copyi_k(const int* __restrict__ src, int* __restrict__ dst, int n) {
    int i = blockIdx.x * blockDim.x + threadIdx.x;
    if (i < n) dst[i] = src[i];
}

__global__ void scatter_k(const int* __restrict__ dst, int* __restrict__ next,
                          int* __restrict__ perm) {
    int e = blockIdx.x * blockDim.x + threadIdx.x;
    if (e < NE) {
        int p = atomicAdd(&next[dst[e]], 1);
        perm[p] = e;
    }
}

__global__ void permsd_k(const int* __restrict__ eidx, const int* __restrict__ perm,
                         int* __restrict__ srcS, int* __restrict__ dstS) {
    int i = blockIdx.x * blockDim.x + threadIdx.x;
    if (i < NE) {
        int e = perm[i];
        srcS[i] = eidx[e];
        dstS[i] = eidx[NE + e];
    }
}

// ---- graph pooling ----

__global__ void zcnt_k(int* __restrict__ cnts) {
    if (threadIdx.x < NG) cnts[threadIdx.x] = 0;
}

__global__ void count_k(const int* __restrict__ batch, int* __restrict__ cnts) {
    int i = blockIdx.x * blockDim.x + threadIdx.x;
    if (i < NN) atomicAdd(&cnts[batch[i]], 1);
}

__global__ void offs_k(const int* __restrict__ cnts, int* __restrict__ offs) {
    if (threadIdx.x == 0) {
        int a = 0;
        for (int g = 0; g < NG; ++g) { offs[g] = a; a += cnts[g]; }
        offs[NG] = a;
    }
}

__global__ void pool_layer_k(const u16* __restrict__ xh, const int* __restrict__ offs,
                             float* __restrict__ pooled, int l) {
    int g = blockIdx.x, t = threadIdx.x;
    int lo = offs[g], hi = offs[g + 1];
    float s = 0.0f;
    for (int n = lo; n < hi; ++n) s += h2f(xh[(size_t)n * HD + t]);
    int c = hi - lo; if (c < 1) c = 1;
    pooled[(size_t)g * (NL * HD) + l * HD + t] = s / (float)c;
}

__global__ void fc_k(const float* __restrict__ pooled,
                     const float* __restrict__ W1, const float* __restrict__ b1,
                     const float* __restrict__ W4, const float* __restrict__ b4,
                     float* __restrict__ out) {
    __shared__ float pl[NL * HD];
    __shared__ float hm[HD];
    int g = blockIdx.x, t = threadIdx.x;
#pragma unroll
    for (int j = 0; j < 4; ++j) pl[t + j * 256] = pooled[(size_t)g * 1024 + t + j * 256];
    __syncthreads();
    float a = b1[t];
    for (int k = 0; k < 1024; ++k) a += pl[k] * W1[k * 256 + t];
    hm[t] = a > 0.0f ? a : 0.0f;
    __syncthreads();
    if (t < OD) {
        float o = b4[t];
        for (int k = 0; k < 256; ++k) o += hm[k] * W4[k * OD + t];
        out[g * OD + t] = o;
    }
}

// ---------------------------------------------------------------------------

extern "C" void kernel_launch(void* const* d_in, const int* in_sizes, int n_in,
                              void* d_out, int out_size, void* d_ws, size_t ws_size,
                              hipStream_t stream) {
    const float* x_in  = (const float*)d_in[0];
    const int*   eidx  = (const int*)d_in[1];
    const float* eattr = (const float*)d_in[2];
    const int*   batch = (const int*)d_in[3];
    const float* bW1   = (const float*)d_in[4];
    const float* bb1   = (const float*)d_in[5];
    const float* bW2   = (const float*)d_in[6];
    const float* bb2   = (const float*)d_in[7];
    const float* mW1   = (const float*)d_in[8];
    const float* mb1   = (const float*)d_in[9];
    const float* mW2   = (const float*)d_in[10];
    const float* mb2   = (const float*)d_in[11];
    const float* epsv  = (const float*)d_in[12];
    const float* gamma = (const float*)d_in[13];
    const float* beta  = (const float*)d_in[14];
    const float* fc1W  = (const float*)d_in[15];
    const float* fc1b  = (const float*)d_in[16];
    const float* fc4W  = (const float*)d_in[17];
    const float* fc4b  = (const float*)d_in[18];
    float* out = (float*)d_out;
    (void)in_sizes; (void)n_in; (void)out_size; (void)ws_size;

    // ---- workspace carve (~148 MB; round-4's ~156 MB ran without fault) ----
    size_t off = 0;
    auto alloc = [&](size_t bytes) -> char* {
        char* r = (char*)d_ws + off;
        off = (off + bytes + 255) & ~(size_t)255;
        return r;
    };
    u16*   xh   = (u16*)alloc((size_t)NN * HD * 2);    // 25.6 MB node feats, fp16
    float* aggr = (float*)alloc((size_t)NN * HD * 4);  // 51.2 MB aggregate, fp32
    u16*   h0hb = (u16*)alloc((size_t)NN * HD * 2);    // 25.6 MB h0, reused as hb
    u16*   W1t  = (u16*)alloc((size_t)NL * FEA * HD * 2);
    u16*   W2t  = (u16*)alloc((size_t)NL * HD * HD * 2);
    u16*   M1t  = (u16*)alloc((size_t)NL * HD * HD * 2);
    u16*   M2t  = (u16*)alloc((size_t)NL * HD * HD * 2);
    float* bns  = (float*)alloc(HD * 4);
    float* bnq  = (float*)alloc(HD * 4);
    float* ab   = (float*)alloc(2 * HD * 4);
    int*   cnts = (int*)alloc(NG * 4);
    int*   offs = (int*)alloc((NG + 1) * 4);
    float* pooled = (float*)alloc((size_t)NG * NL * HD * 4);
    int*   hist  = (int*)alloc((size_t)NN * 4);        // also reused as `next`
    int*   psum  = (int*)alloc((size_t)SCB * 4);
    int*   rowptr = (int*)alloc((size_t)(NN + 1) * 4);
    int*   perm  = (int*)alloc((size_t)NE * 4);
    int*   srcS  = (int*)alloc((size_t)NE * 4);
    int*   dstS  = (int*)alloc((size_t)NE * 4);
    // union region (38.4 MB): edge phase T1 (ECH=75000 rows) | node phase T2
    u16* T1  = (u16*)alloc((size_t)ECH * HD * 2);
    u16* T2  = T1;

    const int NEL = NN * HD;
    const int EB = (NEL + 255) / 256;
    const int NEB = (NE + 255) / 256;

    // weights: fp32 -> fp16, transposed to [N,K]
    transpose_k<<<(NL * FEA * HD + 255) / 256, 256, 0, stream>>>(bW1, W1t, FEA, HD);
    transpose_k<<<(NL * HD * HD + 255) / 256, 256, 0, stream>>>(bW2, W2t, HD, HD);
    transpose_k<<<(NL * HD * HD + 255) / 256, 256, 0, stream>>>(mW1, M1t, HD, HD);
    transpose_k<<<(NL * HD * HD + 255) / 256, 256, 0, stream>>>(mW2, M2t, HD, HD);

    cvt_k<<<EB, 256, 0, stream>>>(x_in, xh, NEL);

    // counting-sort edges by dst: hist -> hierarchical scan -> scatter perm
    zeroi_k<<<(NN + 255) / 256, 256, 0, stream>>>(hist, NN);
    hist_k<<<NEB, 256, 0, stream>>>(eidx + NE, hist);
    sumblk_k<<<SCB, 256, 0, stream>>>(hist, psum);
    scanblk_k<<<1, 256, 0, stream>>>(psum);
    scanfin_k<<<SCB, 256, 0, stream>>>(hist, psum, rowptr);
    copyi_k<<<(NN + 255) / 256, 256, 0, stream>>>(rowptr, hist, NN);   // hist = next
    scatter_k<<<NEB, 256, 0, stream>>>(eidx + NE, hist, perm);
    permsd_k<<<NEB, 256, 0, stream>>>(eidx, perm, srcS, dstS);

    zcnt_k<<<1, 256, 0, stream>>>(cnts);
    count_k<<<(NN + 255) / 256, 256, 0, stream>>>(batch, cnts);
    offs_k<<<1, 64, 0, stream>>>(cnts, offs);

    for (int l = 0; l < NL; ++l) {
        zero_layer_k<<<EB, 256, 0, stream>>>(aggr, bns, bnq);
        // edge path (sorted): gather-GEMM0 -> GEMM1 + dedup-scatter
        for (int c = 0; c < NCH; ++c) {
            const int e0 = c * ECH;
            dim3 g1((ECH + 127) / 128, 2);
            gemm_k<0, 1><<<g1, 256, 0, stream>>>(
                nullptr, eattr, perm, e0,
                W1t + (size_t)l * FEA * HD,
                bb1 + l * HD, ECH, FEA, T1,
                nullptr, nullptr, nullptr, nullptr, nullptr, nullptr);
            gemm_k<1, 0><<<g1, 256, 0, stream>>>(
                T1, nullptr, nullptr, 0,
                W2t + (size_t)l * HD * HD,
                bb2 + l * HD, ECH, HD, nullptr,
                srcS + e0, dstS + e0, xh, aggr, nullptr, nullptr);
        }
        h0_k<<<EB, 256, 0, stream>>>(xh, aggr, h0hb, epsv, l);
        dim3 g2((NN + 127) / 128, 2);
        gemm_k<0, 0><<<g2, 256, 0, stream>>>(
            h0hb, nullptr, nullptr, 0,
            M1t + (size_t)l * HD * HD,
            mb1 + l * HD, NN, HD, T2,
            nullptr, nullptr, nullptr, nullptr, nullptr, nullptr);
        gemm_k<3, 0><<<g2, 256, 0, stream>>>(
            T2, nullptr, nullptr, 0,
            M2t + (size_t)l * HD * HD,
            mb2 + l * HD, NN, HD, h0hb,
            nullptr, nullptr, nullptr, nullptr, bns, bnq);
        bnfin_k<<<1, HD, 0, stream>>>(bns, bnq, gamma, beta, l, ab);
        bnapply_k<<<EB, 256, 0, stream>>>(h0hb, ab, xh);
        pool_layer_k<<<NG, HD, 0, stream>>>(xh, offs, pooled, l);
    }
    fc_k<<<NG, 256, 0, stream>>>(pooled, fc1W, fc1b, fc4W, fc4b, out);
}

// Round 11
// 2160.608 us; speedup vs baseline: 1.9090x; 1.1720x over previous
//
#include <hip/hip_runtime.h>

// Problem constants (from reference)
#define NN 50000      // nodes
#define NE 300000     // edges
#define FEA 64        // edge feature dim
#define HD 256        // hidden
#define NG 256        // graphs
#define NL 4          // layers
#define OD 128        // out dim
#define SCB ((NN + 255) / 256)   // scan blocks = 196

typedef unsigned short u16;
typedef unsigned int u32;
typedef __attribute__((ext_vector_type(8))) short short8;
typedef __attribute__((ext_vector_type(4))) float f32x4;

__device__ __forceinline__ u16 f2h(float f) {
    union { _Float16 h; u16 u; } v; v.h = (_Float16)f; return v.u;
}
__device__ __forceinline__ float h2f(u16 u) {
    union { u16 u; _Float16 h; } v; v.u = u; return (float)v.h;
}

// ---------------------------------------------------------------------------
// Fused edge kernel: per block, 64 sorted edges x full 256 cols.
//   T1 = relu(eattrS @ W1 + b1)      (K=64, T1 kept in LDS only)
//   e  = T1 @ W2 + b2                (K=256, W2 staged in 4 chunks)
//   msg = relu(e + xh[src]) -> run-dedup atomicAdd aggr[dst]
// LDS: bufW 32KB (W1, then W2 k-chunks) + bufT 32KB (eattr tile, then T1).
// XOR-swizzled 16B blocks; 64 KB total -> 2 blocks/CU.
// ---------------------------------------------------------------------------
__global__ __launch_bounds__(256, 2) void edge_k(
    const u16* __restrict__ eattrS, const u16* __restrict__ W1t,
    const float* __restrict__ bb1, const u16* __restrict__ W2t,
    const float* __restrict__ bb2,
    const int* __restrict__ srcI, const int* __restrict__ dstI,
    const u16* __restrict__ xh, float* __restrict__ aggr)
{
    __shared__ __align__(16) u16 bufW[256 * 64];   // 32768 B
    __shared__ __align__(16) u16 bufT[64 * 256];   // 32768 B
    const int tid = threadIdx.x;
    const int lane = tid & 63;
    const int w = tid >> 6;
    const int q = lane >> 4, c15 = lane & 15;
    const int e0 = blockIdx.x * 64;

    // stage eattr tile (64 rows x 64 k) into bufT, swizzled
#pragma unroll
    for (int it = 0; it < 2; ++it) {
        const int i = it * 256 + tid;        // 0..511
        const int m = i >> 3, kb = i & 7;
        int row = e0 + m; if (row > NE - 1) row = NE - 1;
        *(short8*)&bufT[m * 64 + ((kb ^ (m & 7)) * 8)] =
            *(const short8*)(eattrS + (size_t)row * FEA + kb * 8);
    }
    // stage W1 (256 rows x 64 k) into bufW, swizzled
#pragma unroll
    for (int it = 0; it < 8; ++it) {
        const int i = it * 256 + tid;        // 0..2047
        const int n = i >> 3, kb = i & 7;
        *(short8*)&bufW[n * 64 + ((kb ^ (n & 7)) * 8)] =
            *(const short8*)(W1t + (size_t)n * FEA + kb * 8);
    }
    __syncthreads();

    // GEMM1: acc1[64 edges][w*64 + 64 cols], K=64
    f32x4 acc1[4][4];
#pragma unroll
    for (int i = 0; i < 4; ++i)
#pragma unroll
        for (int j = 0; j < 4; ++j) acc1[i][j] = (f32x4)0.0f;
#pragma unroll
    for (int s = 0; s < 2; ++s) {
        short8 af[4], bf[4];
#pragma unroll
        for (int t = 0; t < 4; ++t) {
            const int kga = s * 4 + q;
            const int mm = t * 16 + c15;
            af[t] = *(const short8*)&bufT[mm * 64 + ((kga ^ (mm & 7)) * 8)];
            const int nn = w * 64 + t * 16 + c15;
            bf[t] = *(const short8*)&bufW[nn * 64 + ((kga ^ (nn & 7)) * 8)];
        }
#pragma unroll
        for (int tm = 0; tm < 4; ++tm)
#pragma unroll
            for (int tn = 0; tn < 4; ++tn)
                acc1[tm][tn] = __builtin_amdgcn_mfma_f32_16x16x32_f16(
                    af[tm], bf[tn], acc1[tm][tn], 0, 0, 0);
    }
    __syncthreads();   // all reads of bufT(eattr)/bufW(W1) done

    // T1 = relu(acc1 + b1) -> bufT as [64 rows][256 k], swizzled
    {
        float b1f[4];
#pragma unroll
        for (int tn = 0; tn < 4; ++tn)
            b1f[tn] = bb1[w * 64 + tn * 16 + c15];
#pragma unroll
        for (int tm = 0; tm < 4; ++tm)
#pragma unroll
            for (int tn = 0; tn < 4; ++tn) {
                const int col = w * 64 + tn * 16 + c15;
                const int kb = col >> 3;
#pragma unroll
                for (int r = 0; r < 4; ++r) {
                    const int row = tm * 16 + q * 4 + r;
                    float v = acc1[tm][tn][r] + b1f[tn];
                    v = v > 0.0f ? v : 0.0f;
                    bufT[row * 256 + ((kb ^ (row & 7)) * 8) + (col & 7)] = f2h(v);
                }
            }
    }

    // GEMM2: acc2 = T1 @ W2, K=256 in 4 chunks
    f32x4 acc2[4][4];
#pragma unroll
    for (int i = 0; i < 4; ++i)
#pragma unroll
        for (int j = 0; j < 4; ++j) acc2[i][j] = (f32x4)0.0f;
    for (int k0 = 0; k0 < 256; k0 += 64) {
#pragma unroll
        for (int it = 0; it < 8; ++it) {
            const int i = it * 256 + tid;
            const int n = i >> 3, kbl = i & 7;
            *(short8*)&bufW[n * 64 + ((kbl ^ (n & 7)) * 8)] =
                *(const short8*)(W2t + (size_t)n * HD + k0 + kbl * 8);
        }
        __syncthreads();
#pragma unroll
        for (int s = 0; s < 2; ++s) {
            short8 af[4], bf[4];
#pragma unroll
            for (int t = 0; t < 4; ++t) {
                const int mm = t * 16 + c15;
                const int kbg = (k0 >> 3) + s * 4 + q;
                af[t] = *(const short8*)&bufT[mm * 256 + ((kbg ^ (mm & 7)) * 8)];
                const int nn = w * 64 + t * 16 + c15;
                const int kga = s * 4 + q;
                bf[t] = *(const short8*)&bufW[nn * 64 + ((kga ^ (nn & 7)) * 8)];
            }
#pragma unroll
            for (int tm = 0; tm < 4; ++tm)
#pragma unroll
                for (int tn = 0; tn < 4; ++tn)
                    acc2[tm][tn] = __builtin_amdgcn_mfma_f32_16x16x32_f16(
                        af[tm], bf[tn], acc2[tm][tn], 0, 0, 0);
        }
        __syncthreads();
    }

    // EPI: msg = relu(acc2 + b2 + xh[src]) -> run-dedup atomic scatter
    float b2f[4];
#pragma unroll
    for (int tn = 0; tn < 4; ++tn)
        b2f[tn] = bb2[w * 64 + tn * 16 + c15];
#pragma unroll
    for (int tm = 0; tm < 4; ++tm) {
        const int base = e0 + tm * 16 + q * 4;
        int sn[4], dn[4];
        bool val[4];
#pragma unroll
        for (int r = 0; r < 4; ++r) {
            const int erow = base + r;
            val[r] = erow < NE;
            const int er = val[r] ? erow : (NE - 1);
            sn[r] = srcI[er];
            dn[r] = dstI[er];
        }
#pragma unroll
        for (int tn = 0; tn < 4; ++tn) {
            const int col = w * 64 + tn * 16 + c15;
            float accv = 0.0f;
            int cur = -1;
#pragma unroll
            for (int r = 0; r < 4; ++r) {
                if (val[r]) {
                    float msg = acc2[tm][tn][r] + b2f[tn]
                              + h2f(xh[(size_t)sn[r] * HD + col]);
                    msg = msg > 0.0f ? msg : 0.0f;
                    if (dn[r] != cur) {
                        if (cur >= 0 && accv > 0.0f)
                            unsafeAtomicAdd(&aggr[(size_t)cur * HD + col], accv);
                        cur = dn[r];
                        accv = 0.0f;
                    }
                    accv += msg;
                }
            }
            if (cur >= 0 && accv > 0.0f)
                unsafeAtomicAdd(&aggr[(size_t)cur * HD + col], accv);
        }
    }
}

// ---------------------------------------------------------------------------
// Fused node kernel: per block, 64 nodes x 256 cols.
//   h0 = (1+eps)*x + aggr          (computed in A-staging, fp16 to LDS)
//   T2 = relu(h0 @ M1 + b1)        (LDS only)
//   hb = relu(T2 @ M2 + b2)        -> store + BN sum/sumsq atomics
// ---------------------------------------------------------------------------
__global__ __launch_bounds__(256, 2) void node_k(
    const u16* __restrict__ xh, const float* __restrict__ aggr,
    const float* __restrict__ epsv, int l,
    const u16* __restrict__ M1t, const float* __restrict__ mb1,
    const u16* __restrict__ M2t, const float* __restrict__ mb2,
    u16* __restrict__ hb, float* __restrict__ bns, float* __restrict__ bnq)
{
    __shared__ __align__(16) u16 bufW[256 * 64];   // 32768 B
    __shared__ __align__(16) u16 bufT[64 * 256];   // 32768 B
    const int tid = threadIdx.x;
    const int lane = tid & 63;
    const int w = tid >> 6;
    const int q = lane >> 4, c15 = lane & 15;
    const int n0b = blockIdx.x * 64;
    const float e1 = 1.0f + epsv[l];

    // stage A tile: h0 = (1+eps)*xh + aggr, 64 rows x 256 k, swizzled
#pragma unroll
    for (int it = 0; it < 8; ++it) {
        const int i = it * 256 + tid;        // 0..2047
        const int m = i >> 5, kb = i & 31;
        int row = n0b + m; if (row > NN - 1) row = NN - 1;
        const size_t base = (size_t)row * HD + kb * 8;
        short8 xv = *(const short8*)(xh + base);
        float4 a0 = *(const float4*)(aggr + base);
        float4 a1 = *(const float4*)(aggr + base + 4);
        u16 o[8];
        o[0] = f2h(e1 * h2f((u16)xv[0]) + a0.x);
        o[1] = f2h(e1 * h2f((u16)xv[1]) + a0.y);
        o[2] = f2h(e1 * h2f((u16)xv[2]) + a0.z);
        o[3] = f2h(e1 * h2f((u16)xv[3]) + a0.w);
        o[4] = f2h(e1 * h2f((u16)xv[4]) + a1.x);
        o[5] = f2h(e1 * h2f((u16)xv[5]) + a1.y);
        o[6] = f2h(e1 * h2f((u16)xv[6]) + a1.z);
        o[7] = f2h(e1 * h2f((u16)xv[7]) + a1.w);
        *(short8*)&bufT[m * 256 + ((kb ^ (m & 7)) * 8)] = *(short8*)o;
    }

    // GEMM1: T2acc = h0 @ M1, K=256
    f32x4 acc1[4][4];
#pragma unroll
    for (int i = 0; i < 4; ++i)
#pragma unroll
        for (int j = 0; j < 4; ++j) acc1[i][j] = (f32x4)0.0f;
    for (int k0 = 0; k0 < 256; k0 += 64) {
#pragma unroll
        for (int it = 0; it < 8; ++it) {
            const int i = it * 256 + tid;
            const int n = i >> 3, kbl = i & 7;
            *(short8*)&bufW[n * 64 + ((kbl ^ (n & 7)) * 8)] =
                *(const short8*)(M1t + (size_t)n * HD + k0 + kbl * 8);
        }
        __syncthreads();
#pragma unroll
        for (int s = 0; s < 2; ++s) {
            short8 af[4], bf[4];
#pragma unroll
            for (int t = 0; t < 4; ++t) {
                const int mm = t * 16 + c15;
                const int kbg = (k0 >> 3) + s * 4 + q;
                af[t] = *(const short8*)&bufT[mm * 256 + ((kbg ^ (mm & 7)) * 8)];
                const int nn = w * 64 + t * 16 + c15;
                const int kga = s * 4 + q;
                bf[t] = *(const short8*)&bufW[nn * 64 + ((kga ^ (nn & 7)) * 8)];
            }
#pragma unroll
            for (int tm = 0; tm < 4; ++tm)
#pragma unroll
                for (int tn = 0; tn < 4; ++tn)
                    acc1[tm][tn] = __builtin_amdgcn_mfma_f32_16x16x32_f16(
                        af[tm], bf[tn], acc1[tm][tn], 0, 0, 0);
        }
        __syncthreads();
    }

    // T2 = relu(acc1 + b1) -> bufT (overwrite A tile), swizzled
    {
        float b1f[4];
#pragma unroll
        for (int tn = 0; tn < 4; ++tn)
            b1f[tn] = mb1[w * 64 + tn * 16 + c15];
#pragma unroll
        for (int tm = 0; tm < 4; ++tm)
#pragma unroll
            for (int tn = 0; tn < 4; ++tn) {
                const int col = w * 64 + tn * 16 + c15;
                const int kb = col >> 3;
#pragma unroll
                for (int r = 0; r < 4; ++r) {
                    const int row = tm * 16 + q * 4 + r;
                    float v = acc1[tm][tn][r] + b1f[tn];
                    v = v > 0.0f ? v : 0.0f;
                    bufT[row * 256 + ((kb ^ (row & 7)) * 8) + (col & 7)] = f2h(v);
                }
            }
    }

    // GEMM2: acc2 = T2 @ M2, K=256
    f32x4 acc2[4][4];
#pragma unroll
    for (int i = 0; i < 4; ++i)
#pragma unroll
        for (int j = 0; j < 4; ++j) acc2[i][j] = (f32x4)0.0f;
    for (int k0 = 0; k0 < 256; k0 += 64) {
#pragma unroll
        for (int it = 0; it < 8; ++it) {
            const int i = it * 256 + tid;
            const int n = i >> 3, kbl = i & 7;
            *(short8*)&bufW[n * 64 + ((kbl ^ (n & 7)) * 8)] =
                *(const short8*)(M2t + (size_t)n * HD + k0 + kbl * 8);
        }
        __syncthreads();
#pragma unroll
        for (int s = 0; s < 2; ++s) {
            short8 af[4], bf[4];
#pragma unroll
            for (int t = 0; t < 4; ++t) {
                const int mm = t * 16 + c15;
                const int kbg = (k0 >> 3) + s * 4 + q;
                af[t] = *(const short8*)&bufT[mm * 256 + ((kbg ^ (mm & 7)) * 8)];
                const int nn = w * 64 + t * 16 + c15;
                const int kga = s * 4 + q;
                bf[t] = *(const short8*)&bufW[nn * 64 + ((kga ^ (nn & 7)) * 8)];
            }
#pragma unroll
            for (int tm = 0; tm < 4; ++tm)
#pragma unroll
                for (int tn = 0; tn < 4; ++tn)
                    acc2[tm][tn] = __builtin_amdgcn_mfma_f32_16x16x32_f16(
                        af[tm], bf[tn], acc2[tm][tn], 0, 0, 0);
        }
        __syncthreads();
    }

    // EPI: hb = relu(acc2 + b2) store + BN stats
    float b2f[4];
#pragma unroll
    for (int tn = 0; tn < 4; ++tn)
        b2f[tn] = mb2[w * 64 + tn * 16 + c15];
    float ps[4] = {0, 0, 0, 0}, pq[4] = {0, 0, 0, 0};
#pragma unroll
    for (int tm = 0; tm < 4; ++tm) {
#pragma unroll
        for (int r = 0; r < 4; ++r) {
            const int grow = n0b + tm * 16 + q * 4 + r;
            if (grow < NN) {
#pragma unroll
                for (int tn = 0; tn < 4; ++tn) {
                    const int col = w * 64 + tn * 16 + c15;
                    float v = acc2[tm][tn][r] + b2f[tn];
                    v = v > 0.0f ? v : 0.0f;
                    hb[(size_t)grow * HD + col] = f2h(v);
                    ps[tn] += v; pq[tn] += v * v;
                }
            }
        }
    }
#pragma unroll
    for (int tn = 0; tn < 4; ++tn) {
        float s = ps[tn], sq = pq[tn];
        s += __shfl_down(s, 32, 64);  sq += __shfl_down(sq, 32, 64);
        s += __shfl_down(s, 16, 64);  sq += __shfl_down(sq, 16, 64);
        if (q == 0) {
            const int col = w * 64 + tn * 16 + c15;
            unsafeAtomicAdd(&bns[col], s);
            unsafeAtomicAdd(&bnq[col], sq);
        }
    }
}

// --------------------------- small helper kernels ---------------------------

// fp32 [L,K,N] -> fp16 transposed [L,N,K]
__global__ void transpose_k(const float* __restrict__ in, u16* __restrict__ oh,
                            int Kw, int Nw) {
    int i = blockIdx.x * blockDim.x + threadIdx.x;
    int tot = NL * Kw * Nw;
    if (i < tot) {
        int l = i / (Kw * Nw), rem = i % (Kw * Nw);
        int k = rem / Nw, n = rem % Nw;
        oh[(size_t)l * Kw * Nw + (size_t)n * Kw + k] = f2h(in[i]);
    }
}

__global__ void cvt_k(const float* __restrict__ in, u16* __restrict__ outh, int tot) {
    int i = blockIdx.x * blockDim.x + threadIdx.x;
    if (i < tot) outh[i] = f2h(in[i]);
}

// gather eattr rows into sorted order, fp32 -> fp16
__global__ void egather_k(const float* __restrict__ eattr, const int* __restrict__ perm,
                          u16* __restrict__ eattrS) {
    int i = blockIdx.x * blockDim.x + threadIdx.x;
    if (i < NE * FEA) {
        int row = i >> 6, k = i & 63;
        eattrS[i] = f2h(eattr[(size_t)perm[row] * FEA + k]);
    }
}

__global__ void zero_layer_k(float* __restrict__ aggr, float* __restrict__ bns,
                             float* __restrict__ bnq) {
    int i = blockIdx.x * blockDim.x + threadIdx.x;
    if (i < NN * HD) aggr[i] = 0.0f;
    if (i < HD) { bns[i] = 0.0f; bnq[i] = 0.0f; }
}

__global__ void bnfin_k(const float* __restrict__ bns, const float* __restrict__ bnq,
                        const float* __restrict__ gamma, const float* __restrict__ beta,
                        int l, float* __restrict__ ab) {
    int c = threadIdx.x;
    float mu = bns[c] * (1.0f / (float)NN);
    float var = bnq[c] * (1.0f / (float)NN) - mu * mu;
    if (var < 0.0f) var = 0.0f;
    float a = gamma[l * HD + c] * rsqrtf(var + 1e-5f);
    float b = beta[l * HD + c] - mu * a;
    ab[c] = a; ab[HD + c] = b;
}

__global__ void bnapply_k(const u16* __restrict__ hb, const float* __restrict__ ab,
                          u16* __restrict__ xh) {
    int i = blockIdx.x * blockDim.x + threadIdx.x;
    if (i < NN * HD) {
        int c = i & (HD - 1);
        xh[i] = f2h(ab[c] * h2f(hb[i]) + ab[HD + c]);
    }
}

// ---- edge counting-sort by dst (hierarchical scan) ----

__global__ void zeroi_k(int* __restrict__ a, int n) {
    int i = blockIdx.x * blockDim.x + threadIdx.x;
    if (i < n) a[i] = 0;
}

__global__ void hist_k(const int* __restrict__ dst, int* __restrict__ hist) {
    int e = blockIdx.x * blockDim.x + threadIdx.x;
    if (e < NE) atomicAdd(&hist[dst[e]], 1);
}

__global__ void sumblk_k(const int* __restrict__ hist, int* __restrict__ psum) {
    __shared__ int red[256];
    int b = blockIdx.x, t = threadIdx.x, i = b * 256 + t;
    red[t] = (i < NN) ? hist[i] : 0;
    __syncthreads();
    for (int o = 128; o > 0; o >>= 1) {
        if (t < o) red[t] += red[t + o];
        __syncthreads();
    }
    if (t == 0) psum[b] = red[0];
}

__global__ void scanblk_k(int* __restrict__ psum) {
    __shared__ int sc[256];
    int t = threadIdx.x;
    int v = (t < SCB) ? psum[t] : 0;
    sc[t] = v; __syncthreads();
    for (int o = 1; o < 256; o <<= 1) {
        int x = (t >= o) ? sc[t - o] : 0;
        __syncthreads(); sc[t] += x; __syncthreads();
    }
    if (t < SCB) psum[t] = sc[t] - v;   // exclusive
}

__global__ void scanfin_k(const int* __restrict__ hist, const int* __restrict__ psum,
                          int* __restrict__ rowptr) {
    __shared__ int sc[256];
    int b = blockIdx.x, t = threadIdx.x, i = b * 256 + t;
    int v = (i < NN) ? hist[i] : 0;
    sc[t] = v; __syncthreads();
    for (int o = 1; o < 256; o <<= 1) {
        int x = (t >= o) ? sc[t - o] : 0;
        __syncthreads(); sc[t] += x; __syncthreads();
    }
    if (i < NN) rowptr[i] = psum[b] + sc[t] - v;
    if (i == NN - 1) rowptr[NN] = psum[b] + sc[t];
}

__global__ void copyi_k(const int* __restrict__ src, int* __restrict__ dst, int n) {
    int i = blockIdx.x * blockDim.x + threadIdx.x;
    if (i < n) dst[i] = src[i];
}

__global__ void scatter_k(const int* __restrict__ dst, int* __restrict__ next,
                          int* __restrict__ perm) {
    int e = blockIdx.x * blockDim.x + threadIdx.x;
    if (e < NE) {
        int p = atomicAdd(&next[dst[e]], 1);
        perm[p] = e;
    }
}

__global__ void permsd_k(const int* __restrict__ eidx, const int* __restrict__ perm,
                         int* __restrict__ srcS, int* __restrict__ dstS) {
    int i = blockIdx.x * blockDim.x + threadIdx.x;
    if (i < NE) {
        int e = perm[i];
        srcS[i] = eidx[e];
        dstS[i] = eidx[NE + e];
    }
}

// ---- graph pooling ----

__global__ void zcnt_k(int* __restrict__ cnts) {
    if (threadIdx.x < NG) cnts[threadIdx.x] = 0;
}

__global__ void count_k(const int* __restrict__ batch, int* __restrict__ cnts) {
    int i = blockIdx.x * blockDim.x + threadIdx.x;
    if (i < NN) atomicAdd(&cnts[batch[i]], 1);
}

__global__ void offs_k(const int* __restrict__ cnts, int* __restrict__ offs) {
    if (threadIdx.x == 0) {
        int a = 0;
        for (int g = 0; g < NG; ++g) { offs[g] = a; a += cnts[g]; }
        offs[NG] = a;
    }
}

__global__ void pool_layer_k(const u16* __restrict__ xh, const int* __restrict__ offs,
                             float* __restrict__ pooled, int l) {
    int g = blockIdx.x, t = threadIdx.x;
    int lo = offs[g], hi = offs[g + 1];
    float s = 0.0f;
    for (int n = lo; n < hi; ++n) s += h2f(xh[(size_t)n * HD + t]);
    int c = hi - lo; if (c < 1) c = 1;
    pooled[(size_t)g * (NL * HD) + l * HD + t] = s / (float)c;
}

__global__ void fc_k(const float* __restrict__ pooled,
                     const float* __restrict__ W1, const float* __restrict__ b1,
                     const float* __restrict__ W4, const float* __restrict__ b4,
                     float* __restrict__ out) {
    __shared__ float pl[NL * HD];
    __shared__ float hm[HD];
    int g = blockIdx.x, t = threadIdx.x;
#pragma unroll
    for (int j = 0; j < 4; ++j) pl[t + j * 256] = pooled[(size_t)g * 1024 + t + j * 256];
    __syncthreads();
    float a = b1[t];
    for (int k = 0; k < 1024; ++k) a += pl[k] * W1[k * 256 + t];
    hm[t] = a > 0.0f ? a : 0.0f;
    __syncthreads();
    if (t < OD) {
        float o = b4[t];
        for (int k = 0; k < 256; ++k) o += hm[k] * W4[k * OD + t];
        out[g * OD + t] = o;
    }
}

// ---------------------------------------------------------------------------

extern "C" void kernel_launch(void* const* d_in, const int* in_sizes, int n_in,
                              void* d_out, int out_size, void* d_ws, size_t ws_size,
                              hipStream_t stream) {
    const float* x_in  = (const float*)d_in[0];
    const int*   eidx  = (const int*)d_in[1];
    const float* eattr = (const float*)d_in[2];
    const int*   batch = (const int*)d_in[3];
    const float* bW1   = (const float*)d_in[4];
    const float* bb1   = (const float*)d_in[5];
    const float* bW2   = (const float*)d_in[6];
    const float* bb2   = (const float*)d_in[7];
    const float* mW1   = (const float*)d_in[8];
    const float* mb1   = (const float*)d_in[9];
    const float* mW2   = (const float*)d_in[10];
    const float* mb2   = (const float*)d_in[11];
    const float* epsv  = (const float*)d_in[12];
    const float* gamma = (const float*)d_in[13];
    const float* beta  = (const float*)d_in[14];
    const float* fc1W  = (const float*)d_in[15];
    const float* fc1b  = (const float*)d_in[16];
    const float* fc4W  = (const float*)d_in[17];
    const float* fc4b  = (const float*)d_in[18];
    float* out = (float*)d_out;
    (void)in_sizes; (void)n_in; (void)out_size; (void)ws_size;

    // ---- workspace carve (~148 MB; ~156 MB proven safe in round 4) ----
    size_t off = 0;
    auto alloc = [&](size_t bytes) -> char* {
        char* r = (char*)d_ws + off;
        off = (off + bytes + 255) & ~(size_t)255;
        return r;
    };
    u16*   xh   = (u16*)alloc((size_t)NN * HD * 2);    // 25.6 MB node feats, fp16
    float* aggr = (float*)alloc((size_t)NN * HD * 4);  // 51.2 MB aggregate, fp32
    u16*   hb   = (u16*)alloc((size_t)NN * HD * 2);    // 25.6 MB MLP out pre-BN
    u16*   eattrS = (u16*)alloc((size_t)NE * FEA * 2); // 38.4 MB sorted fp16 eattr
    u16*   W1t  = (u16*)alloc((size_t)NL * FEA * HD * 2);
    u16*   W2t  = (u16*)alloc((size_t)NL * HD * HD * 2);
    u16*   M1t  = (u16*)alloc((size_t)NL * HD * HD * 2);
    u16*   M2t  = (u16*)alloc((size_t)NL * HD * HD * 2);
    float* bns  = (float*)alloc(HD * 4);
    float* bnq  = (float*)alloc(HD * 4);
    float* ab   = (float*)alloc(2 * HD * 4);
    int*   cnts = (int*)alloc(NG * 4);
    int*   offs = (int*)alloc((NG + 1) * 4);
    float* pooled = (float*)alloc((size_t)NG * NL * HD * 4);
    int*   hist  = (int*)alloc((size_t)NN * 4);        // also reused as `next`
    int*   psum  = (int*)alloc((size_t)SCB * 4);
    int*   rowptr = (int*)alloc((size_t)(NN + 1) * 4);
    int*   perm  = (int*)alloc((size_t)NE * 4);
    int*   srcS  = (int*)alloc((size_t)NE * 4);
    int*   dstS  = (int*)alloc((size_t)NE * 4);

    const int NEL = NN * HD;
    const int EB = (NEL + 255) / 256;
    const int NEB = (NE + 255) / 256;

    // weights: fp32 -> fp16, transposed to [N,K]
    transpose_k<<<(NL * FEA * HD + 255) / 256, 256, 0, stream>>>(bW1, W1t, FEA, HD);
    transpose_k<<<(NL * HD * HD + 255) / 256, 256, 0, stream>>>(bW2, W2t, HD, HD);
    transpose_k<<<(NL * HD * HD + 255) / 256, 256, 0, stream>>>(mW1, M1t, HD, HD);
    transpose_k<<<(NL * HD * HD + 255) / 256, 256, 0, stream>>>(mW2, M2t, HD, HD);

    cvt_k<<<EB, 256, 0, stream>>>(x_in, xh, NEL);

    // counting-sort edges by dst: hist -> hierarchical scan -> scatter perm
    zeroi_k<<<(NN + 255) / 256, 256, 0, stream>>>(hist, NN);
    hist_k<<<NEB, 256, 0, stream>>>(eidx + NE, hist);
    sumblk_k<<<SCB, 256, 0, stream>>>(hist, psum);
    scanblk_k<<<1, 256, 0, stream>>>(psum);
    scanfin_k<<<SCB, 256, 0, stream>>>(hist, psum, rowptr);
    copyi_k<<<(NN + 255) / 256, 256, 0, stream>>>(rowptr, hist, NN);   // hist = next
    scatter_k<<<NEB, 256, 0, stream>>>(eidx + NE, hist, perm);
    permsd_k<<<NEB, 256, 0, stream>>>(eidx, perm, srcS, dstS);
    egather_k<<<(NE * FEA + 255) / 256, 256, 0, stream>>>(eattr, perm, eattrS);

    zcnt_k<<<1, 256, 0, stream>>>(cnts);
    count_k<<<(NN + 255) / 256, 256, 0, stream>>>(batch, cnts);
    offs_k<<<1, 64, 0, stream>>>(cnts, offs);

    const int EGB = (NE + 63) / 64;    // 4688 edge blocks
    const int NGB = (NN + 63) / 64;    // 782 node blocks

    for (int l = 0; l < NL; ++l) {
        zero_layer_k<<<EB, 256, 0, stream>>>(aggr, bns, bnq);
        edge_k<<<EGB, 256, 0, stream>>>(
            eattrS, W1t + (size_t)l * FEA * HD, bb1 + l * HD,
            W2t + (size_t)l * HD * HD, bb2 + l * HD,
            srcS, dstS, xh, aggr);
        node_k<<<NGB, 256, 0, stream>>>(
            xh, aggr, epsv, l,
            M1t + (size_t)l * HD * HD, mb1 + l * HD,
            M2t + (size_t)l * HD * HD, mb2 + l * HD,
            hb, bns, bnq);
        bnfin_k<<<1, HD, 0, stream>>>(bns, bnq, gamma, beta, l, ab);
        bnapply_k<<<EB, 256, 0, stream>>>(hb, ab, xh);
        pool_layer_k<<<NG, HD, 0, stream>>>(xh, offs, pooled, l);
    }
    fc_k<<<NG, 256, 0, stream>>>(pooled, fc1W, fc1b, fc4W, fc4b, out);
}

// Round 12
// 1548.980 us; speedup vs baseline: 2.6627x; 1.3949x over previous
//
#include <hip/hip_runtime.h>

// Problem constants (from reference)
#define NN 50000      // nodes
#define NE 300000     // edges
#define FEA 64        // edge feature dim
#define HD 256        // hidden
#define NG 256        // graphs
#define NL 4          // layers
#define OD 128        // out dim
#define SCB ((NN + 255) / 256)   // scan blocks = 196

typedef unsigned short u16;
typedef unsigned int u32;
typedef __attribute__((ext_vector_type(8))) short short8;
typedef __attribute__((ext_vector_type(4))) float f32x4;

__device__ __forceinline__ u16 f2h(float f) {
    union { _Float16 h; u16 u; } v; v.h = (_Float16)f; return v.u;
}
__device__ __forceinline__ float h2f(u16 u) {
    union { u16 u; _Float16 h; } v; v.u = u; return (float)v.h;
}

// ---------------------------------------------------------------------------
// Fused edge kernel: per block, 64 sorted edges x full 256 cols.
//   T1 = relu(eattrS @ W1 + b1)      (K=64, LDS only)
//   e  = T1 @ W2 + b2                (K=256, W2 staged in 4 chunks)
//   msg = relu(e + xh[src])          (xh rows pre-gathered coalesced into LDS)
//   aggr += segmented-sum(msg)       (per-block run reduction, ~1 atomic/node)
// LDS: bufW 32KB (W1 / W2 chunks / xh gather) + bufT 32KB (eattr / T1 / msg).
// ---------------------------------------------------------------------------
__global__ __launch_bounds__(256, 2) void edge_k(
    const u16* __restrict__ eattrS, const u16* __restrict__ W1t,
    const float* __restrict__ bb1, const u16* __restrict__ W2t,
    const float* __restrict__ bb2,
    const int* __restrict__ srcI, const int* __restrict__ dstI,
    const u16* __restrict__ xh, float* __restrict__ aggr)
{
    __shared__ __align__(16) u16 bufW[256 * 64];   // 32768 B
    __shared__ __align__(16) u16 bufT[64 * 256];   // 32768 B
    __shared__ int dstL[64];
    const int tid = threadIdx.x;
    const int lane = tid & 63;
    const int w = tid >> 6;
    const int q = lane >> 4, c15 = lane & 15;
    const int e0 = blockIdx.x * 64;

    // stage eattr tile (64 rows x 64 k) into bufT, swizzled
#pragma unroll
    for (int it = 0; it < 2; ++it) {
        const int i = it * 256 + tid;        // 0..511
        const int m = i >> 3, kb = i & 7;
        int row = e0 + m; if (row > NE - 1) row = NE - 1;
        *(short8*)&bufT[m * 64 + ((kb ^ (m & 7)) * 8)] =
            *(const short8*)(eattrS + (size_t)row * FEA + kb * 8);
    }
    // stage W1 (256 rows x 64 k) into bufW, swizzled
#pragma unroll
    for (int it = 0; it < 8; ++it) {
        const int i = it * 256 + tid;        // 0..2047
        const int n = i >> 3, kb = i & 7;
        *(short8*)&bufW[n * 64 + ((kb ^ (n & 7)) * 8)] =
            *(const short8*)(W1t + (size_t)n * FEA + kb * 8);
    }
    if (tid < 64) {
        int er = e0 + tid;
        dstL[tid] = (er < NE) ? dstI[er] : -1;
    }
    __syncthreads();

    // GEMM1: acc1[64 edges][w*64 + 64 cols], K=64
    f32x4 acc1[4][4];
#pragma unroll
    for (int i = 0; i < 4; ++i)
#pragma unroll
        for (int j = 0; j < 4; ++j) acc1[i][j] = (f32x4)0.0f;
#pragma unroll
    for (int s = 0; s < 2; ++s) {
        short8 af[4], bf[4];
#pragma unroll
        for (int t = 0; t < 4; ++t) {
            const int kga = s * 4 + q;
            const int mm = t * 16 + c15;
            af[t] = *(const short8*)&bufT[mm * 64 + ((kga ^ (mm & 7)) * 8)];
            const int nn = w * 64 + t * 16 + c15;
            bf[t] = *(const short8*)&bufW[nn * 64 + ((kga ^ (nn & 7)) * 8)];
        }
#pragma unroll
        for (int tm = 0; tm < 4; ++tm)
#pragma unroll
            for (int tn = 0; tn < 4; ++tn)
                acc1[tm][tn] = __builtin_amdgcn_mfma_f32_16x16x32_f16(
                    af[tm], bf[tn], acc1[tm][tn], 0, 0, 0);
    }
    __syncthreads();   // all reads of bufT(eattr)/bufW(W1) done

    // T1 = relu(acc1 + b1) -> bufT as [64 rows][256 k], swizzled
    {
        float b1f[4];
#pragma unroll
        for (int tn = 0; tn < 4; ++tn)
            b1f[tn] = bb1[w * 64 + tn * 16 + c15];
#pragma unroll
        for (int tm = 0; tm < 4; ++tm)
#pragma unroll
            for (int tn = 0; tn < 4; ++tn) {
                const int col = w * 64 + tn * 16 + c15;
                const int kb = col >> 3;
#pragma unroll
                for (int r = 0; r < 4; ++r) {
                    const int row = tm * 16 + q * 4 + r;
                    float v = acc1[tm][tn][r] + b1f[tn];
                    v = v > 0.0f ? v : 0.0f;
                    bufT[row * 256 + ((kb ^ (row & 7)) * 8) + (col & 7)] = f2h(v);
                }
            }
    }

    // GEMM2: acc2 = T1 @ W2, K=256 in 4 chunks
    f32x4 acc2[4][4];
#pragma unroll
    for (int i = 0; i < 4; ++i)
#pragma unroll
        for (int j = 0; j < 4; ++j) acc2[i][j] = (f32x4)0.0f;
    for (int k0 = 0; k0 < 256; k0 += 64) {
#pragma unroll
        for (int it = 0; it < 8; ++it) {
            const int i = it * 256 + tid;
            const int n = i >> 3, kbl = i & 7;
            *(short8*)&bufW[n * 64 + ((kbl ^ (n & 7)) * 8)] =
                *(const short8*)(W2t + (size_t)n * HD + k0 + kbl * 8);
        }
        __syncthreads();
#pragma unroll
        for (int s = 0; s < 2; ++s) {
            short8 af[4], bf[4];
#pragma unroll
            for (int t = 0; t < 4; ++t) {
                const int mm = t * 16 + c15;
                const int kbg = (k0 >> 3) + s * 4 + q;
                af[t] = *(const short8*)&bufT[mm * 256 + ((kbg ^ (mm & 7)) * 8)];
                const int nn = w * 64 + t * 16 + c15;
                const int kga = s * 4 + q;
                bf[t] = *(const short8*)&bufW[nn * 64 + ((kga ^ (nn & 7)) * 8)];
            }
#pragma unroll
            for (int tm = 0; tm < 4; ++tm)
#pragma unroll
                for (int tn = 0; tn < 4; ++tn)
                    acc2[tm][tn] = __builtin_amdgcn_mfma_f32_16x16x32_f16(
                        af[tm], bf[tn], acc2[tm][tn], 0, 0, 0);
        }
        __syncthreads();
    }

    // cooperative coalesced gather: xh[src] rows -> bufW [64][256] (unswizzled)
#pragma unroll
    for (int it = 0; it < 8; ++it) {
        const int idx = it * 256 + tid;   // 0..2047
        const int row = idx >> 5;         // 0..63
        const int ch = idx & 31;          // 16B chunk in 512B row
        int er = e0 + row; if (er > NE - 1) er = NE - 1;
        const int sn = srcI[er];
        *(short8*)&bufW[row * 256 + ch * 8] =
            *(const short8*)(xh + (size_t)sn * HD + ch * 8);
    }
    __syncthreads();

    // msg = relu(acc2 + b2 + xh_gather) -> bufT [64][256] fp16 (unswizzled)
    {
        float b2f[4];
#pragma unroll
        for (int tn = 0; tn < 4; ++tn)
            b2f[tn] = bb2[w * 64 + tn * 16 + c15];
#pragma unroll
        for (int tm = 0; tm < 4; ++tm)
#pragma unroll
            for (int r = 0; r < 4; ++r) {
                const int row = tm * 16 + q * 4 + r;
                if (e0 + row < NE) {
#pragma unroll
                    for (int tn = 0; tn < 4; ++tn) {
                        const int col = w * 64 + tn * 16 + c15;
                        float v = acc2[tm][tn][r] + b2f[tn]
                                + h2f(bufW[row * 256 + col]);
                        v = v > 0.0f ? v : 0.0f;
                        bufT[row * 256 + col] = f2h(v);
                    }
                }
            }
    }
    __syncthreads();

    // segmented reduction: thread t = col t, walk sorted rows, 1 atomic per run
    {
        const int hiR = (NE - e0 < 64) ? (NE - e0) : 64;
        float s = 0.0f;
        int cur = dstL[0];
        for (int rI = 0; rI < hiR; ++rI) {
            const int d = dstL[rI];
            if (d != cur) {
                if (s != 0.0f) unsafeAtomicAdd(&aggr[(size_t)cur * HD + tid], s);
                cur = d; s = 0.0f;
            }
            s += h2f(bufT[rI * 256 + tid]);
        }
        if (cur >= 0 && s != 0.0f)
            unsafeAtomicAdd(&aggr[(size_t)cur * HD + tid], s);
    }
}

// ---------------------------------------------------------------------------
// Fused node kernel: per block, 64 nodes x 256 cols.
//   h0 = (1+eps)*x + aggr          (computed in A-staging, fp16 to LDS)
//   T2 = relu(h0 @ M1 + b1)        (LDS only)
//   hb = relu(T2 @ M2 + b2)        -> store + BN sum/sumsq atomics
// ---------------------------------------------------------------------------
__global__ __launch_bounds__(256, 2) void node_k(
    const u16* __restrict__ xh, const float* __restrict__ aggr,
    const float* __restrict__ epsv, int l,
    const u16* __restrict__ M1t, const float* __restrict__ mb1,
    const u16* __restrict__ M2t, const float* __restrict__ mb2,
    u16* __restrict__ hb, float* __restrict__ bns, float* __restrict__ bnq)
{
    __shared__ __align__(16) u16 bufW[256 * 64];   // 32768 B
    __shared__ __align__(16) u16 bufT[64 * 256];   // 32768 B
    const int tid = threadIdx.x;
    const int lane = tid & 63;
    const int w = tid >> 6;
    const int q = lane >> 4, c15 = lane & 15;
    const int n0b = blockIdx.x * 64;
    const float e1 = 1.0f + epsv[l];

    // stage A tile: h0 = (1+eps)*xh + aggr, 64 rows x 256 k, swizzled
#pragma unroll
    for (int it = 0; it < 8; ++it) {
        const int i = it * 256 + tid;        // 0..2047
        const int m = i >> 5, kb = i & 31;
        int row = n0b + m; if (row > NN - 1) row = NN - 1;
        const size_t base = (size_t)row * HD + kb * 8;
        short8 xv = *(const short8*)(xh + base);
        float4 a0 = *(const float4*)(aggr + base);
        float4 a1 = *(const float4*)(aggr + base + 4);
        u16 o[8];
        o[0] = f2h(e1 * h2f((u16)xv[0]) + a0.x);
        o[1] = f2h(e1 * h2f((u16)xv[1]) + a0.y);
        o[2] = f2h(e1 * h2f((u16)xv[2]) + a0.z);
        o[3] = f2h(e1 * h2f((u16)xv[3]) + a0.w);
        o[4] = f2h(e1 * h2f((u16)xv[4]) + a1.x);
        o[5] = f2h(e1 * h2f((u16)xv[5]) + a1.y);
        o[6] = f2h(e1 * h2f((u16)xv[6]) + a1.z);
        o[7] = f2h(e1 * h2f((u16)xv[7]) + a1.w);
        *(short8*)&bufT[m * 256 + ((kb ^ (m & 7)) * 8)] = *(short8*)o;
    }

    // GEMM1: T2acc = h0 @ M1, K=256
    f32x4 acc1[4][4];
#pragma unroll
    for (int i = 0; i < 4; ++i)
#pragma unroll
        for (int j = 0; j < 4; ++j) acc1[i][j] = (f32x4)0.0f;
    for (int k0 = 0; k0 < 256; k0 += 64) {
#pragma unroll
        for (int it = 0; it < 8; ++it) {
            const int i = it * 256 + tid;
            const int n = i >> 3, kbl = i & 7;
            *(short8*)&bufW[n * 64 + ((kbl ^ (n & 7)) * 8)] =
                *(const short8*)(M1t + (size_t)n * HD + k0 + kbl * 8);
        }
        __syncthreads();
#pragma unroll
        for (int s = 0; s < 2; ++s) {
            short8 af[4], bf[4];
#pragma unroll
            for (int t = 0; t < 4; ++t) {
                const int mm = t * 16 + c15;
                const int kbg = (k0 >> 3) + s * 4 + q;
                af[t] = *(const short8*)&bufT[mm * 256 + ((kbg ^ (mm & 7)) * 8)];
                const int nn = w * 64 + t * 16 + c15;
                const int kga = s * 4 + q;
                bf[t] = *(const short8*)&bufW[nn * 64 + ((kga ^ (nn & 7)) * 8)];
            }
#pragma unroll
            for (int tm = 0; tm < 4; ++tm)
#pragma unroll
                for (int tn = 0; tn < 4; ++tn)
                    acc1[tm][tn] = __builtin_amdgcn_mfma_f32_16x16x32_f16(
                        af[tm], bf[tn], acc1[tm][tn], 0, 0, 0);
        }
        __syncthreads();
    }

    // T2 = relu(acc1 + b1) -> bufT (overwrite A tile), swizzled
    {
        float b1f[4];
#pragma unroll
        for (int tn = 0; tn < 4; ++tn)
            b1f[tn] = mb1[w * 64 + tn * 16 + c15];
#pragma unroll
        for (int tm = 0; tm < 4; ++tm)
#pragma unroll
            for (int tn = 0; tn < 4; ++tn) {
                const int col = w * 64 + tn * 16 + c15;
                const int kb = col >> 3;
#pragma unroll
                for (int r = 0; r < 4; ++r) {
                    const int row = tm * 16 + q * 4 + r;
                    float v = acc1[tm][tn][r] + b1f[tn];
                    v = v > 0.0f ? v : 0.0f;
                    bufT[row * 256 + ((kb ^ (row & 7)) * 8) + (col & 7)] = f2h(v);
                }
            }
    }

    // GEMM2: acc2 = T2 @ M2, K=256
    f32x4 acc2[4][4];
#pragma unroll
    for (int i = 0; i < 4; ++i)
#pragma unroll
        for (int j = 0; j < 4; ++j) acc2[i][j] = (f32x4)0.0f;
    for (int k0 = 0; k0 < 256; k0 += 64) {
#pragma unroll
        for (int it = 0; it < 8; ++it) {
            const int i = it * 256 + tid;
            const int n = i >> 3, kbl = i & 7;
            *(short8*)&bufW[n * 64 + ((kbl ^ (n & 7)) * 8)] =
                *(const short8*)(M2t + (size_t)n * HD + k0 + kbl * 8);
        }
        __syncthreads();
#pragma unroll
        for (int s = 0; s < 2; ++s) {
            short8 af[4], bf[4];
#pragma unroll
            for (int t = 0; t < 4; ++t) {
                const int mm = t * 16 + c15;
                const int kbg = (k0 >> 3) + s * 4 + q;
                af[t] = *(const short8*)&bufT[mm * 256 + ((kbg ^ (mm & 7)) * 8)];
                const int nn = w * 64 + t * 16 + c15;
                const int kga = s * 4 + q;
                bf[t] = *(const short8*)&bufW[nn * 64 + ((kga ^ (nn & 7)) * 8)];
            }
#pragma unroll
            for (int tm = 0; tm < 4; ++tm)
#pragma unroll
                for (int tn = 0; tn < 4; ++tn)
                    acc2[tm][tn] = __builtin_amdgcn_mfma_f32_16x16x32_f16(
                        af[tm], bf[tn], acc2[tm][tn], 0, 0, 0);
        }
        __syncthreads();
    }

    // EPI: hb = relu(acc2 + b2) store + BN stats
    float b2f[4];
#pragma unroll
    for (int tn = 0; tn < 4; ++tn)
        b2f[tn] = mb2[w * 64 + tn * 16 + c15];
    float ps[4] = {0, 0, 0, 0}, pq[4] = {0, 0, 0, 0};
#pragma unroll
    for (int tm = 0; tm < 4; ++tm) {
#pragma unroll
        for (int r = 0; r < 4; ++r) {
            const int grow = n0b + tm * 16 + q * 4 + r;
            if (grow < NN) {
#pragma unroll
                for (int tn = 0; tn < 4; ++tn) {
                    const int col = w * 64 + tn * 16 + c15;
                    float v = acc2[tm][tn][r] + b2f[tn];
                    v = v > 0.0f ? v : 0.0f;
                    hb[(size_t)grow * HD + col] = f2h(v);
                    ps[tn] += v; pq[tn] += v * v;
                }
            }
        }
    }
#pragma unroll
    for (int tn = 0; tn < 4; ++tn) {
        float s = ps[tn], sq = pq[tn];
        s += __shfl_down(s, 32, 64);  sq += __shfl_down(sq, 32, 64);
        s += __shfl_down(s, 16, 64);  sq += __shfl_down(sq, 16, 64);
        if (q == 0) {
            const int col = w * 64 + tn * 16 + c15;
            unsafeAtomicAdd(&bns[col], s);
            unsafeAtomicAdd(&bnq[col], sq);
        }
    }
}

// --------------------------- small helper kernels ---------------------------

// fp32 [L,K,N] -> fp16 transposed [L,N,K]
__global__ void transpose_k(const float* __restrict__ in, u16* __restrict__ oh,
                            int Kw, int Nw) {
    int i = blockIdx.x * blockDim.x + threadIdx.x;
    int tot = NL * Kw * Nw;
    if (i < tot) {
        int l = i / (Kw * Nw), rem = i % (Kw * Nw);
        int k = rem / Nw, n = rem % Nw;
        oh[(size_t)l * Kw * Nw + (size_t)n * Kw + k] = f2h(in[i]);
    }
}

__global__ void cvt_k(const float* __restrict__ in, u16* __restrict__ outh, int tot) {
    int i = blockIdx.x * blockDim.x + threadIdx.x;
    if (i < tot) outh[i] = f2h(in[i]);
}

// gather eattr rows into sorted order, fp32 -> fp16
__global__ void egather_k(const float* __restrict__ eattr, const int* __restrict__ perm,
                          u16* __restrict__ eattrS) {
    int i = blockIdx.x * blockDim.x + threadIdx.x;
    if (i < NE * FEA) {
        int row = i >> 6, k = i & 63;
        eattrS[i] = f2h(eattr[(size_t)perm[row] * FEA + k]);
    }
}

__global__ void zero_layer_k(float* __restrict__ aggr, float* __restrict__ bns,
                             float* __restrict__ bnq) {
    int i = blockIdx.x * blockDim.x + threadIdx.x;
    if (i < NN * HD) aggr[i] = 0.0f;
    if (i < HD) { bns[i] = 0.0f; bnq[i] = 0.0f; }
}

__global__ void bnfin_k(const float* __restrict__ bns, const float* __restrict__ bnq,
                        const float* __restrict__ gamma, const float* __restrict__ beta,
                        int l, float* __restrict__ ab) {
    int c = threadIdx.x;
    float mu = bns[c] * (1.0f / (float)NN);
    float var = bnq[c] * (1.0f / (float)NN) - mu * mu;
    if (var < 0.0f) var = 0.0f;
    float a = gamma[l * HD + c] * rsqrtf(var + 1e-5f);
    float b = beta[l * HD + c] - mu * a;
    ab[c] = a; ab[HD + c] = b;
}

__global__ void bnapply_k(const u16* __restrict__ hb, const float* __restrict__ ab,
                          u16* __restrict__ xh) {
    int i = blockIdx.x * blockDim.x + threadIdx.x;
    if (i < NN * HD) {
        int c = i & (HD - 1);
        xh[i] = f2h(ab[c] * h2f(hb[i]) + ab[HD + c]);
    }
}

// ---- edge counting-sort by dst (hierarchical scan) ----

__global__ void zeroi_k(int* __restrict__ a, int n) {
    int i = blockIdx.x * blockDim.x + threadIdx.x;
    if (i < n) a[i] = 0;
}

__global__ void hist_k(const int* __restrict__ dst, int* __restrict__ hist) {
    int e = blockIdx.x * blockDim.x + threadIdx.x;
    if (e < NE) atomicAdd(&hist[dst[e]], 1);
}

__global__ void sumblk_k(const int* __restrict__ hist, int* __restrict__ psum) {
    __shared__ int red[256];
    int b = blockIdx.x, t = threadIdx.x, i = b * 256 + t;
    red[t] = (i < NN) ? hist[i] : 0;
    __syncthreads();
    for (int o = 128; o > 0; o >>= 1) {
        if (t < o) red[t] += red[t + o];
        __syncthreads();
    }
    if (t == 0) psum[b] = red[0];
}

__global__ void scanblk_k(int* __restrict__ psum) {
    __shared__ int sc[256];
    int t = threadIdx.x;
    int v = (t < SCB) ? psum[t] : 0;
    sc[t] = v; __syncthreads();
    for (int o = 1; o < 256; o <<= 1) {
        int x = (t >= o) ? sc[t - o] : 0;
        __syncthreads(); sc[t] += x; __syncthreads();
    }
    if (t < SCB) psum[t] = sc[t] - v;   // exclusive
}

__global__ void scanfin_k(const int* __restrict__ hist, const int* __restrict__ psum,
                          int* __restrict__ rowptr) {
    __shared__ int sc[256];
    int b = blockIdx.x, t = threadIdx.x, i = b * 256 + t;
    int v = (i < NN) ? hist[i] : 0;
    sc[t] = v; __syncthreads();
    for (int o = 1; o < 256; o <<= 1) {
        int x = (t >= o) ? sc[t - o] : 0;
        __syncthreads(); sc[t] += x; __syncthreads();
    }
    if (i < NN) rowptr[i] = psum[b] + sc[t] - v;
    if (i == NN - 1) rowptr[NN] = psum[b] + sc[t];
}

__global__ void copyi_k(const int* __restrict__ src, int* __restrict__ dst, int n) {
    int i = blockIdx.x * blockDim.x + threadIdx.x;
    if (i < n) dst[i] = src[i];
}

__global__ void scatter_k(const int* __restrict__ dst, int* __restrict__ next,
                          int* __restrict__ perm) {
    int e = blockIdx.x * blockDim.x + threadIdx.x;
    if (e < NE) {
        int p = atomicAdd(&next[dst[e]], 1);
        perm[p] = e;
    }
}

__global__ void permsd_k(const int* __restrict__ eidx, const int* __restrict__ perm,
                         int* __restrict__ srcS, int* __restrict__ dstS) {
    int i = blockIdx.x * blockDim.x + threadIdx.x;
    if (i < NE) {
        int e = perm[i];
        srcS[i] = eidx[e];
        dstS[i] = eidx[NE + e];
    }
}

// ---- graph pooling ----

__global__ void zcnt_k(int* __restrict__ cnts) {
    if (threadIdx.x < NG) cnts[threadIdx.x] = 0;
}

__global__ void count_k(const int* __restrict__ batch, int* __restrict__ cnts) {
    int i = blockIdx.x * blockDim.x + threadIdx.x;
    if (i < NN) atomicAdd(&cnts[batch[i]], 1);
}

__global__ void offs_k(const int* __restrict__ cnts, int* __restrict__ offs) {
    if (threadIdx.x == 0) {
        int a = 0;
        for (int g = 0; g < NG; ++g) { offs[g] = a; a += cnts[g]; }
        offs[NG] = a;
    }
}

__global__ void pool_layer_k(const u16* __restrict__ xh, const int* __restrict__ offs,
                             float* __restrict__ pooled, int l) {
    int g = blockIdx.x, t = threadIdx.x;
    int lo = offs[g], hi = offs[g + 1];
    float s = 0.0f;
    for (int n = lo; n < hi; ++n) s += h2f(xh[(size_t)n * HD + t]);
    int c = hi - lo; if (c < 1) c = 1;
    pooled[(size_t)g * (NL * HD) + l * HD + t] = s / (float)c;
}

__global__ void fc_k(const float* __restrict__ pooled,
                     const float* __restrict__ W1, const float* __restrict__ b1,
                     const float* __restrict__ W4, const float* __restrict__ b4,
                     float* __restrict__ out) {
    __shared__ float pl[NL * HD];
    __shared__ float hm[HD];
    int g = blockIdx.x, t = threadIdx.x;
#pragma unroll
    for (int j = 0; j < 4; ++j) pl[t + j * 256] = pooled[(size_t)g * 1024 + t + j * 256];
    __syncthreads();
    float a = b1[t];
    for (int k = 0; k < 1024; ++k) a += pl[k] * W1[k * 256 + t];
    hm[t] = a > 0.0f ? a : 0.0f;
    __syncthreads();
    if (t < OD) {
        float o = b4[t];
        for (int k = 0; k < 256; ++k) o += hm[k] * W4[k * OD + t];
        out[g * OD + t] = o;
    }
}

// ---------------------------------------------------------------------------

extern "C" void kernel_launch(void* const* d_in, const int* in_sizes, int n_in,
                              void* d_out, int out_size, void* d_ws, size_t ws_size,
                              hipStream_t stream) {
    const float* x_in  = (const float*)d_in[0];
    const int*   eidx  = (const int*)d_in[1];
    const float* eattr = (const float*)d_in[2];
    const int*   batch = (const int*)d_in[3];
    const float* bW1   = (const float*)d_in[4];
    const float* bb1   = (const float*)d_in[5];
    const float* bW2   = (const float*)d_in[6];
    const float* bb2   = (const float*)d_in[7];
    const float* mW1   = (const float*)d_in[8];
    const float* mb1   = (const float*)d_in[9];
    const float* mW2   = (const float*)d_in[10];
    const float* mb2   = (const float*)d_in[11];
    const float* epsv  = (const float*)d_in[12];
    const float* gamma = (const float*)d_in[13];
    const float* beta  = (const float*)d_in[14];
    const float* fc1W  = (const float*)d_in[15];
    const float* fc1b  = (const float*)d_in[16];
    const float* fc4W  = (const float*)d_in[17];
    const float* fc4b  = (const float*)d_in[18];
    float* out = (float*)d_out;
    (void)in_sizes; (void)n_in; (void)out_size; (void)ws_size;

    // ---- workspace carve (~148 MB; ~156 MB proven safe in round 4) ----
    size_t off = 0;
    auto alloc = [&](size_t bytes) -> char* {
        char* r = (char*)d_ws + off;
        off = (off + bytes + 255) & ~(size_t)255;
        return r;
    };
    u16*   xh   = (u16*)alloc((size_t)NN * HD * 2);    // 25.6 MB node feats, fp16
    float* aggr = (float*)alloc((size_t)NN * HD * 4);  // 51.2 MB aggregate, fp32
    u16*   hb   = (u16*)alloc((size_t)NN * HD * 2);    // 25.6 MB MLP out pre-BN
    u16*   eattrS = (u16*)alloc((size_t)NE * FEA * 2); // 38.4 MB sorted fp16 eattr
    u16*   W1t  = (u16*)alloc((size_t)NL * FEA * HD * 2);
    u16*   W2t  = (u16*)alloc((size_t)NL * HD * HD * 2);
    u16*   M1t  = (u16*)alloc((size_t)NL * HD * HD * 2);
    u16*   M2t  = (u16*)alloc((size_t)NL * HD * HD * 2);
    float* bns  = (float*)alloc(HD * 4);
    float* bnq  = (float*)alloc(HD * 4);
    float* ab   = (float*)alloc(2 * HD * 4);
    int*   cnts = (int*)alloc(NG * 4);
    int*   offs = (int*)alloc((NG + 1) * 4);
    float* pooled = (float*)alloc((size_t)NG * NL * HD * 4);
    int*   hist  = (int*)alloc((size_t)NN * 4);        // also reused as `next`
    int*   psum  = (int*)alloc((size_t)SCB * 4);
    int*   rowptr = (int*)alloc((size_t)(NN + 1) * 4);
    int*   perm  = (int*)alloc((size_t)NE * 4);
    int*   srcS  = (int*)alloc((size_t)NE * 4);
    int*   dstS  = (int*)alloc((size_t)NE * 4);

    const int NEL = NN * HD;
    const int EB = (NEL + 255) / 256;
    const int NEB = (NE + 255) / 256;

    // weights: fp32 -> fp16, transposed to [N,K]
    transpose_k<<<(NL * FEA * HD + 255) / 256, 256, 0, stream>>>(bW1, W1t, FEA, HD);
    transpose_k<<<(NL * HD * HD + 255) / 256, 256, 0, stream>>>(bW2, W2t, HD, HD);
    transpose_k<<<(NL * HD * HD + 255) / 256, 256, 0, stream>>>(mW1, M1t, HD, HD);
    transpose_k<<<(NL * HD * HD + 255) / 256, 256, 0, stream>>>(mW2, M2t, HD, HD);

    cvt_k<<<EB, 256, 0, stream>>>(x_in, xh, NEL);

    // counting-sort edges by dst: hist -> hierarchical scan -> scatter perm
    zeroi_k<<<(NN + 255) / 256, 256, 0, stream>>>(hist, NN);
    hist_k<<<NEB, 256, 0, stream>>>(eidx + NE, hist);
    sumblk_k<<<SCB, 256, 0, stream>>>(hist, psum);
    scanblk_k<<<1, 256, 0, stream>>>(psum);
    scanfin_k<<<SCB, 256, 0, stream>>>(hist, psum, rowptr);
    copyi_k<<<(NN + 255) / 256, 256, 0, stream>>>(rowptr, hist, NN);   // hist = next
    scatter_k<<<NEB, 256, 0, stream>>>(eidx + NE, hist, perm);
    permsd_k<<<NEB, 256, 0, stream>>>(eidx, perm, srcS, dstS);
    egather_k<<<(NE * FEA + 255) / 256, 256, 0, stream>>>(eattr, perm, eattrS);

    zcnt_k<<<1, 256, 0, stream>>>(cnts);
    count_k<<<(NN + 255) / 256, 256, 0, stream>>>(batch, cnts);
    offs_k<<<1, 64, 0, stream>>>(cnts, offs);

    const int EGB = (NE + 63) / 64;    // 4688 edge blocks
    const int NGB = (NN + 63) / 64;    // 782 node blocks

    for (int l = 0; l < NL; ++l) {
        zero_layer_k<<<EB, 256, 0, stream>>>(aggr, bns, bnq);
        edge_k<<<EGB, 256, 0, stream>>>(
            eattrS, W1t + (size_t)l * FEA * HD, bb1 + l * HD,
            W2t + (size_t)l * HD * HD, bb2 + l * HD,
            srcS, dstS, xh, aggr);
        node_k<<<NGB, 256, 0, stream>>>(
            xh, aggr, epsv, l,
            M1t + (size_t)l * HD * HD, mb1 + l * HD,
            M2t + (size_t)l * HD * HD, mb2 + l * HD,
            hb, bns, bnq);
        bnfin_k<<<1, HD, 0, stream>>>(bns, bnq, gamma, beta, l, ab);
        bnapply_k<<<EB, 256, 0, stream>>>(hb, ab, xh);
        pool_layer_k<<<NG, HD, 0, stream>>>(xh, offs, pooled, l);
    }
    fc_k<<<NG, 256, 0, stream>>>(pooled, fc1W, fc1b, fc4W, fc4b, out);
}